// Round 8
// baseline (151.631 us; speedup 1.0000x reference)
//
#include <hip/hip_runtime.h>
#include <hip/hip_bf16.h>

typedef __bf16 bf16;
typedef __bf16 bf16x8 __attribute__((ext_vector_type(8)));
typedef __bf16 bf16x2 __attribute__((ext_vector_type(2)));
typedef float f32x4 __attribute__((ext_vector_type(4)));
typedef unsigned short u16;
typedef unsigned short u16x8 __attribute__((ext_vector_type(8)));
typedef unsigned int u32;

constexpr int kHW = 1024;
constexpr int kC  = 512;

__device__ inline float wave_sum(float v) {
#pragma unroll
    for (int o = 32; o; o >>= 1) v += __shfl_xor(v, o, 64);
    return v;
}

__device__ inline float b2f(u16 u) {
    union { float f; unsigned i; } z; z.i = ((unsigned)u) << 16; return z.f;
}

__device__ inline void gload_lds16(const void* g, void* l) {
    __builtin_amdgcn_global_load_lds(
        (const __attribute__((address_space(1))) void*)g,
        (__attribute__((address_space(3))) void*)l, 16, 0, 0);
}

#define VMCNT(n) asm volatile("s_waitcnt vmcnt(" #n ")" ::: "memory")
#define SBAR __builtin_amdgcn_s_barrier()
#define NOP do {} while (0)

// ---------------- weights f32->bf16 + bias pack ----------------
__global__ __launch_bounds__(256) void wconv_kernel(
    const float* __restrict__ wq, const float* __restrict__ wk,
    const float* __restrict__ wv, const float* __restrict__ wp,
    const float* __restrict__ bq, const float* __restrict__ bk,
    const float* __restrict__ bv, const float* __restrict__ bp,
    bf16* __restrict__ dst, float* __restrict__ bpk)
{
    int i = blockIdx.x * 256 + threadIdx.x;
    dst[i]            = (bf16)wq[i];
    dst[262144 + i]   = (bf16)wk[i];
    dst[2*262144 + i] = (bf16)wv[i];
    dst[3*262144 + i] = (bf16)wp[i];
    if (i < 2048) {
        int j = i >> 9, c = i & 511;
        const float* s = j == 0 ? bq : j == 1 ? bk : j == 2 ? bv : bp;
        bpk[i] = s[c];
    }
}

// ---------------- GN pass 1: per-(tensor,b,g) mean/rstd -------------------
__global__ __launch_bounds__(256) void gn_stats(
    const float* __restrict__ x0, const float* __restrict__ x1,
    float* __restrict__ st)              // [2][16][32][2]
{
    int sel = blockIdx.x >> 9, blk = blockIdx.x & 511;
    const float* x = sel ? x1 : x0;
    int b = blk >> 5, g = blk & 31;
    const float4* xg4 = reinterpret_cast<const float4*>(
        x + ((size_t)b * kC + g * 16) * kHW);

    float s = 0.f, s2 = 0.f;
#pragma unroll
    for (int i = 0; i < 16; ++i) {
        float4 v = xg4[threadIdx.x + i * 256];
        s  += v.x + v.y + v.z + v.w;
        s2 += v.x*v.x + v.y*v.y + v.z*v.z + v.w*v.w;
    }
    s = wave_sum(s); s2 = wave_sum(s2);
    __shared__ float red[8];
    int lane = threadIdx.x & 63, wid = threadIdx.x >> 6;
    if (!lane) { red[wid] = s; red[4 + wid] = s2; }
    __syncthreads();
    if (threadIdx.x == 0) {
        float ts = red[0] + red[1] + red[2] + red[3];
        float t2 = red[4] + red[5] + red[6] + red[7];
        float mean = ts * (1.f / 16384.f);
        float var  = t2 * (1.f / 16384.f) - mean * mean;
        st[blockIdx.x * 2]     = mean;
        st[blockIdx.x * 2 + 1] = rsqrtf(var + 1e-6f);
    }
}

// ---------------- GN pass 2: apply + transpose, 64ch x 128sp tiles --------
// Reads x [c][hw] coalesced, normalizes, LDS-transposes, writes outT
// [hw][c] in 128B full-line segments. 18KB LDS -> 8 blocks/CU.
__global__ __launch_bounds__(256) void gn_apply(
    const float* __restrict__ x0, const float* __restrict__ s0,
    const float* __restrict__ b0, bf16* __restrict__ o0,
    const float* __restrict__ x1, const float* __restrict__ s1,
    const float* __restrict__ b1, bf16* __restrict__ o1,
    const float* __restrict__ st)
{
    __shared__ u16 tile[128 * 72];       // [sp][ch], row stride 72 bf16
    __shared__ float avec[64], dvec[64];

    int bid = blockIdx.x;
    int sel = bid >> 10, r = bid & 1023;
    int b = r >> 6, cs = (r >> 3) & 7, ss = r & 7;
    int c0 = cs * 64, sp0 = ss * 128;

    const float* x = sel ? x1 : x0;
    const float* scale = sel ? s1 : s0;
    const float* bias  = sel ? b1 : b0;
    bf16* outT = sel ? o1 : o0;

    int t = threadIdx.x;
    if (t < 64) {
        int ch = c0 + t;
        const float* sp_ = st + (((size_t)sel * 16 + b) * 32 + (ch >> 4)) * 2;
        float a = sp_[1] * scale[ch];
        avec[t] = a;
        dvec[t] = bias[ch] - sp_[0] * a;
    }
    __syncthreads();

    // load + normalize + LDS write (transposed)
    const float* xb = x + (size_t)b * kC * kHW + sp0;
#pragma unroll
    for (int ci = 0; ci < 2; ++ci) {
#pragma unroll
        for (int si = 0; si < 4; ++si) {
            int chl = 2 * (t >> 4) + ci * 32;          // local even channel
            int spl = 2 * (t & 15) + si * 32;
            const float* p0 = xb + (size_t)(c0 + chl) * kHW + spl;
            float2 v0 = *reinterpret_cast<const float2*>(p0);
            float2 v1 = *reinterpret_cast<const float2*>(p0 + kHW);
            float a0 = avec[chl], d0 = dvec[chl];
            float a1 = avec[chl + 1], d1 = dvec[chl + 1];
            bf16x2 w0, w1;
            w0[0] = (bf16)(v0.x * a0 + d0); w0[1] = (bf16)(v1.x * a1 + d1);
            w1[0] = (bf16)(v0.y * a0 + d0); w1[1] = (bf16)(v1.y * a1 + d1);
            *reinterpret_cast<bf16x2*>(&tile[spl * 72 + chl])       = w0;
            *reinterpret_cast<bf16x2*>(&tile[(spl + 1) * 72 + chl]) = w1;
        }
    }
    __syncthreads();

    // LDS read (b128, conflict-free) + 128B-segment global store
    bf16* ob = outT + ((size_t)b * kHW + sp0) * kC + c0;
#pragma unroll
    for (int pp = 0; pp < 4; ++pp) {
        int sp = (t >> 3) + pp * 32;
        int part = t & 7;
        u16x8 v = *reinterpret_cast<const u16x8*>(&tile[sp * 72 + part * 8]);
        *reinterpret_cast<u16x8*>(ob + (size_t)sp * kC + part * 8) = v;
    }
}

// ======== 256x256 8-phase NT GEMM, K=512. Schedule v2 =====================
template <int BIAS, bool RESID, typename OUT_T, bool STATS, int NBX, int NBY>
__global__ __launch_bounds__(512, 2) void gemm256(
    const bf16* __restrict__ Ab, size_t sA, int lda,
    const bf16* __restrict__ Bb, size_t sB, int ldb,
    OUT_T* __restrict__ Cb, size_t sC, int ldc,
    const float* __restrict__ biasB, int sBias,
    const float* __restrict__ residB, size_t sR,
    float alpha, float* __restrict__ statsOut)
{
    __shared__ u16 lds[65536];           // 128KB: A 8x8KB (2slot x 4q), B same
    constexpr int NT = 8;                // K = 512

    int bid = blockIdx.x, nwg = gridDim.x;
    int swz = (bid & 7) * (nwg >> 3) + (bid >> 3);
    int job = swz / (NBX * NBY), rem = swz % (NBX * NBY);
    int by = rem / NBX, bx = rem % NBX;
    int brow = by * 256, bcol = bx * 256;

    const u16* Au = reinterpret_cast<const u16*>(Ab + (size_t)job * sA);
    const u16* Bu = reinterpret_cast<const u16*>(Bb + (size_t)job * sB);

    int t = threadIdx.x;
    int lane = t & 63, w = t >> 6;
    int wm = w >> 2, wn = w & 3;
    int cc = lane & 15, nib = lane >> 4;

    int trow = t >> 3;                               // 0..63
    int gsrc = ((t & 7) ^ (trow & 7)) * 8;           // pre-swizzled src granule
    const u16* Asrc = Au + (size_t)(brow + trow) * lda + gsrc;
    const u16* Bsrc = Bu + (size_t)(bcol + trow) * ldb + gsrc;
    u16* LDSA = lds;
    u16* LDSB = lds + 32768;

#define STAGE_A(TL, Q) gload_lds16(Asrc + (size_t)(Q) * 64 * lda + (TL) * 64, \
                                   LDSA + (((TL)&1)*4 + (Q)) * 4096 + t * 8)
#define STAGE_B(TL, Q) gload_lds16(Bsrc + (size_t)(Q) * 64 * ldb + (TL) * 64, \
                                   LDSB + (((TL)&1)*4 + (Q)) * 4096 + t * 8)

    f32x4 acc[8][4] = {};
    bf16x8 afr[4][2], bfr[4][2];

#define PHASE(MH, NH, TL, STG, WTC)                                           \
  {                                                                           \
    if ((NH) == 0) {                                                          \
      _Pragma("unroll") for (int mi = 0; mi < 4; ++mi)                        \
      _Pragma("unroll") for (int kx = 0; kx < 2; ++kx)                        \
        afr[mi][kx] = *reinterpret_cast<const bf16x8*>(LDSA +                 \
            (((TL)&1)*4 + wm*2 + (MH)) * 4096 + (mi*16 + cc) * 64 +           \
            (((nib + kx*4) ^ (cc & 7)) * 8));                                 \
    }                                                                         \
    if ((MH) == 0) {                                                          \
      _Pragma("unroll") for (int ni = 0; ni < 2; ++ni)                        \
      _Pragma("unroll") for (int kx = 0; kx < 2; ++kx)                        \
        bfr[(NH)*2 + ni][kx] = *reinterpret_cast<const bf16x8*>(LDSB +        \
            (((TL)&1)*4 + wn) * 4096 + (((NH)*2 + ni)*16 + cc) * 64 +         \
            (((nib + kx*4) ^ (cc & 7)) * 8));                                 \
    }                                                                         \
    STG;                                                                      \
    SBAR;                                                                     \
    __builtin_amdgcn_s_setprio(1);                                            \
    _Pragma("unroll") for (int mi = 0; mi < 4; ++mi)                          \
    _Pragma("unroll") for (int ni = 0; ni < 2; ++ni)                          \
    _Pragma("unroll") for (int kx = 0; kx < 2; ++kx)                          \
      acc[(MH)*4 + mi][(NH)*2 + ni] = __builtin_amdgcn_mfma_f32_16x16x32_bf16(\
          afr[mi][kx], bfr[(NH)*2 + ni][kx], acc[(MH)*4 + mi][(NH)*2 + ni],   \
          0, 0, 0);                                                           \
    __builtin_amdgcn_s_setprio(0);                                            \
    WTC;                                                                      \
    SBAR;                                                                     \
  }

    // prologue: tiles 0 and 1 fully staged; wait for tile 0
    STAGE_A(0, 0); STAGE_A(0, 2); STAGE_B(0, 0); STAGE_B(0, 1);
    STAGE_B(0, 2); STAGE_B(0, 3); STAGE_A(0, 1); STAGE_A(0, 3);
    STAGE_A(1, 0); STAGE_A(1, 2); STAGE_B(1, 0); STAGE_B(1, 1);
    STAGE_B(1, 2); STAGE_B(1, 3); STAGE_A(1, 1); STAGE_A(1, 3);
    VMCNT(8);
    SBAR;

#pragma unroll
    for (int kt = 0; kt < NT; ++kt) {
        PHASE(0, 0, kt, NOP, NOP);
        PHASE(0, 1, kt,
              if (kt + 2 < NT) { STAGE_A(kt + 2, 0); STAGE_A(kt + 2, 2); },
              NOP);
        PHASE(1, 0, kt,
              if (kt + 2 < NT) { STAGE_B(kt + 2, 0); STAGE_B(kt + 2, 1); },
              NOP);
        PHASE(1, 1, kt,
              if (kt + 2 < NT) { STAGE_B(kt + 2, 2); STAGE_B(kt + 2, 3);
                                 STAGE_A(kt + 2, 1); STAGE_A(kt + 2, 3); },
              if (kt < NT - 2) { VMCNT(8); } else if (kt == NT - 2) { VMCNT(0); });
    }
#undef PHASE
#undef STAGE_A
#undef STAGE_B

#pragma unroll
    for (int m = 0; m < 8; ++m)
#pragma unroll
        for (int n = 0; n < 4; ++n)
#pragma unroll
            for (int r = 0; r < 4; ++r)
                acc[m][n][r] *= alpha;

    if constexpr (STATS) {
        float* sredM = reinterpret_cast<float*>(lds);          // [4][256]
        float* sredS = reinterpret_cast<float*>(lds) + 1024;   // [4][256]
        float rmax[8][4];
#pragma unroll
        for (int m = 0; m < 8; ++m)
#pragma unroll
            for (int r = 0; r < 4; ++r) {
                float v_ = fmaxf(fmaxf(acc[m][0][r], acc[m][1][r]),
                                 fmaxf(acc[m][2][r], acc[m][3][r]));
                v_ = fmaxf(v_, __shfl_xor(v_, 1, 64));
                v_ = fmaxf(v_, __shfl_xor(v_, 2, 64));
                v_ = fmaxf(v_, __shfl_xor(v_, 4, 64));
                v_ = fmaxf(v_, __shfl_xor(v_, 8, 64));
                rmax[m][r] = v_;
            }
        if (cc == 0)
#pragma unroll
            for (int m = 0; m < 8; ++m)
#pragma unroll
                for (int r = 0; r < 4; ++r)
                    sredM[wn * 256 + wm * 128 + m * 16 + nib * 4 + r] = rmax[m][r];
        __syncthreads();
#pragma unroll
        for (int m = 0; m < 8; ++m)
#pragma unroll
            for (int r = 0; r < 4; ++r) {
                int lr = wm * 128 + m * 16 + nib * 4 + r;
                rmax[m][r] = fmaxf(fmaxf(sredM[lr], sredM[256 + lr]),
                                   fmaxf(sredM[512 + lr], sredM[768 + lr]));
            }
#pragma unroll
        for (int m = 0; m < 8; ++m)
#pragma unroll
            for (int r = 0; r < 4; ++r) {
                float s_ = 0.f;
#pragma unroll
                for (int n = 0; n < 4; ++n) {
                    float e = __expf(acc[m][n][r] - rmax[m][r]);
                    acc[m][n][r] = e;
                    s_ += e;
                }
                s_ += __shfl_xor(s_, 1, 64);
                s_ += __shfl_xor(s_, 2, 64);
                s_ += __shfl_xor(s_, 4, 64);
                s_ += __shfl_xor(s_, 8, 64);
                if (cc == 0)
                    sredS[wn * 256 + wm * 128 + m * 16 + nib * 4 + r] = s_;
            }
        __syncthreads();
        if (t < 256) {
            float M = fmaxf(fmaxf(sredM[t], sredM[256 + t]),
                            fmaxf(sredM[512 + t], sredM[768 + t]));
            float L = sredS[t] + sredS[256 + t] + sredS[512 + t] + sredS[768 + t];
            size_t off = ((size_t)(job * 1024 + brow + t)) * 8 + bx * 2;
            statsOut[off]     = M;
            statsOut[off + 1] = L;
        }
    }

    OUT_T* Cj = Cb + (size_t)job * sC;
    const float* bias = biasB + (size_t)job * sBias;
#pragma unroll
    for (int m = 0; m < 8; ++m) {
#pragma unroll
        for (int n = 0; n < 4; ++n) {
#pragma unroll
            for (int r = 0; r < 4; ++r) {
                int grow = brow + wm * 128 + m * 16 + nib * 4 + r;
                int gcol = bcol + wn * 64 + n * 16 + cc;
                float vv = acc[m][n][r];
                if (BIAS == 1) vv += bias[grow];
                if (BIAS == 2) vv += bias[gcol];
                if (RESID)     vv += residB[(size_t)job * sR + (size_t)grow * ldc + gcol];
                Cj[(size_t)grow * ldc + gcol] = (OUT_T)vv;
            }
        }
    }
}

// ======== 128x256 NT GEMM, BK=64, ring-3 slots, 1 barrier/tile ============
template <int BIAS, bool RESID, typename OUT_T, int NBX, int NBY>
__global__ __launch_bounds__(512, 2) void gemm128(
    const bf16* __restrict__ Ab, size_t sA, int lda,
    const bf16* __restrict__ Bb, size_t sB, int ldb,
    OUT_T* __restrict__ Cb, size_t sC, int ldc,
    const float* __restrict__ biasB, int sBias,
    const float* __restrict__ residB, size_t sR)
{
    __shared__ u16 lds[3 * 24576];       // 144KB: 3 slots x (A 16KB + B 32KB)
    constexpr int NT = 8;

    int bid = blockIdx.x, nwg = gridDim.x;
    int swz = (bid & 7) * (nwg >> 3) + (bid >> 3);
    int job = swz / (NBX * NBY), rem = swz % (NBX * NBY);
    int by = rem / NBX, bx = rem % NBX;
    int brow = by * 128, bcol = bx * 256;

    const u16* Au = reinterpret_cast<const u16*>(Ab + (size_t)job * sA);
    const u16* Bu = reinterpret_cast<const u16*>(Bb + (size_t)job * sB);

    int t = threadIdx.x;
    int lane = t & 63, w = t >> 6;
    int wm = w >> 2, wn = w & 3;         // wm 0..1 (M), wn 0..3 (N)
    int cc = lane & 15, nib = lane >> 4;

    int trow = t >> 3;
    int gsrc = ((t & 7) ^ (trow & 7)) * 8;
    const u16* Asrc = Au + (size_t)(brow + trow) * lda + gsrc;
    const u16* Bsrc = Bu + (size_t)(bcol + trow) * ldb + gsrc;

#define STG_T(TL) {                                                           \
    u16* sl_ = lds + ((TL) % 3) * 24576;                                      \
    gload_lds16(Asrc + (TL) * 64,                          sl_ + t * 8);      \
    gload_lds16(Asrc + (size_t)64 * lda + (TL) * 64,       sl_ + 4096 + t*8); \
    gload_lds16(Bsrc + (TL) * 64,                          sl_ + 8192 + t*8); \
    gload_lds16(Bsrc + (size_t)64  * ldb + (TL) * 64,      sl_ + 12288 + t*8);\
    gload_lds16(Bsrc + (size_t)128 * ldb + (TL) * 64,      sl_ + 16384 + t*8);\
    gload_lds16(Bsrc + (size_t)192 * ldb + (TL) * 64,      sl_ + 20480 + t*8);\
  }

    f32x4 acc[4][4] = {};

    STG_T(0); STG_T(1);
    VMCNT(6);
    SBAR;

#pragma unroll
    for (int kt = 0; kt < NT; ++kt) {
        if (kt + 2 < NT) STG_T(kt + 2);
        const u16* sb = lds + (kt % 3) * 24576;
        bf16x8 a[4][2], b[4][2];
#pragma unroll
        for (int mi = 0; mi < 4; ++mi)
#pragma unroll
            for (int kx = 0; kx < 2; ++kx)
                a[mi][kx] = *reinterpret_cast<const bf16x8*>(sb +
                    wm * 4096 + (mi*16 + cc) * 64 + (((nib + kx*4) ^ (cc & 7)) * 8));
#pragma unroll
        for (int ni = 0; ni < 4; ++ni)
#pragma unroll
            for (int kx = 0; kx < 2; ++kx)
                b[ni][kx] = *reinterpret_cast<const bf16x8*>(sb + 8192 +
                    wn * 4096 + (ni*16 + cc) * 64 + (((nib + kx*4) ^ (cc & 7)) * 8));
        __builtin_amdgcn_s_setprio(1);
#pragma unroll
        for (int mi = 0; mi < 4; ++mi)
#pragma unroll
            for (int ni = 0; ni < 4; ++ni)
#pragma unroll
                for (int kx = 0; kx < 2; ++kx)
                    acc[mi][ni] = __builtin_amdgcn_mfma_f32_16x16x32_bf16(
                        a[mi][kx], b[ni][kx], acc[mi][ni], 0, 0, 0);
        __builtin_amdgcn_s_setprio(0);
        if (kt < NT - 2) { VMCNT(6); } else if (kt == NT - 2) { VMCNT(0); }
        SBAR;
    }
#undef STG_T

    OUT_T* Cj = Cb + (size_t)job * sC;
    const float* bias = biasB + (size_t)job * sBias;
#pragma unroll
    for (int mi = 0; mi < 4; ++mi) {
#pragma unroll
        for (int ni = 0; ni < 4; ++ni) {
#pragma unroll
            for (int r = 0; r < 4; ++r) {
                int grow = brow + wm * 64 + mi * 16 + nib * 4 + r;
                int gcol = bcol + wn * 64 + ni * 16 + cc;
                float vv = acc[mi][ni][r];
                if (BIAS == 1) vv += bias[grow];
                if (BIAS == 2) vv += bias[gcol];
                if (RESID)     vv += residB[(size_t)job * sR + (size_t)grow * ldc + gcol];
                Cj[(size_t)grow * ldc + gcol] = (OUT_T)vv;
            }
        }
    }
}

// ======== PV: O = (P_local * alpha_blk) . V^T / L ==========================
__global__ __launch_bounds__(512, 2) void pv_gemm(
    const bf16* __restrict__ P, const float* __restrict__ stats,
    const bf16* __restrict__ V, bf16* __restrict__ O)
{
    __shared__ u16 ldsA[2][4096];        // 128 x 32
    __shared__ u16 ldsB[2][8192];        // 256 x 32
    __shared__ float Ml[128], Ll[128], Mb[4][128];

    int bid = blockIdx.x;
    int swz = (bid & 7) * 32 + (bid >> 3);       // nwg = 256
    int job = swz >> 4, rem = swz & 15;
    int by = rem >> 1, bx = rem & 1;             // 8 x 2 tiles
    int brow = by * 128, bcol = bx * 256;

    int t = threadIdx.x;
    int lane = t & 63, w = t >> 6;
    int wm = w >> 2, wn = w & 3;
    int cc = lane & 15, nib = lane >> 4;

    if (t < 128) {
        const float* st = stats + ((size_t)(job * 1024 + brow + t)) * 8;
        float M = st[0];
#pragma unroll
        for (int k = 1; k < 4; ++k) M = fmaxf(M, st[2 * k]);
        float L = 0.f;
#pragma unroll
        for (int k = 0; k < 4; ++k) L += st[2 * k + 1] * __expf(st[2 * k] - M);
        Ml[t] = M; Ll[t] = L;
        Mb[0][t] = st[0]; Mb[1][t] = st[2]; Mb[2][t] = st[4]; Mb[3][t] = st[6];
    }
    __syncthreads();

    int ar = t >> 2, ag = t & 3;                 // A: row, col-group
    int asw = ((ag ^ ((ar >> 1) & 3))) * 8;      // swizzled write col
    float alf[4];
#pragma unroll
    for (int k = 0; k < 4; ++k) alf[k] = __expf(Mb[k][ar] - Ml[ar]);

    const u16* Pr = reinterpret_cast<const u16*>(P) + (size_t)job * 1048576
                    + (size_t)(brow + ar) * 1024 + ag * 8;
    int br = t >> 1;
    const u16* Vr = reinterpret_cast<const u16*>(V) + (size_t)job * 524288
                    + (size_t)(bcol + br) * 1024 + (t & 1) * 16;
    int bg0 = (t & 1) * 2, bg1 = bg0 + 1;
    int bsw0 = (bg0 ^ ((br >> 1) & 3)) * 8;
    int bsw1 = (bg1 ^ ((br >> 1) & 3)) * 8;
    int rsw = (nib ^ ((cc >> 1) & 3)) * 8;       // swizzled read col

    f32x4 acc[4][4] = {};

    {
        u16x8 p8 = *reinterpret_cast<const u16x8*>(Pr);
        u16x8 v0 = *reinterpret_cast<const u16x8*>(Vr);
        u16x8 v1 = *reinterpret_cast<const u16x8*>(Vr + 8);
        float af = alf[0];
        bf16x8 pw;
#pragma unroll
        for (int j = 0; j < 8; ++j) pw[j] = (bf16)(b2f(p8[j]) * af);
        *reinterpret_cast<bf16x8*>(&ldsA[0][ar * 32 + asw]) = pw;
        *reinterpret_cast<u16x8*>(&ldsB[0][br * 32 + bsw0]) = v0;
        *reinterpret_cast<u16x8*>(&ldsB[0][br * 32 + bsw1]) = v1;
    }
    __syncthreads();

#pragma unroll
    for (int kt = 0; kt < 32; ++kt) {
        int cur = kt & 1;
        u16x8 p8, v0, v1;
        if (kt < 31) {                            // T14: issue loads early
            p8 = *reinterpret_cast<const u16x8*>(Pr + (kt + 1) * 32);
            v0 = *reinterpret_cast<const u16x8*>(Vr + (kt + 1) * 32);
            v1 = *reinterpret_cast<const u16x8*>(Vr + (kt + 1) * 32 + 8);
        }
        bf16x8 a[4], b[4];
#pragma unroll
        for (int mi = 0; mi < 4; ++mi)
            a[mi] = *reinterpret_cast<const bf16x8*>(
                &ldsA[cur][(wm * 64 + mi * 16 + cc) * 32 + rsw]);
#pragma unroll
        for (int ni = 0; ni < 4; ++ni)
            b[ni] = *reinterpret_cast<const bf16x8*>(
                &ldsB[cur][(wn * 64 + ni * 16 + cc) * 32 + rsw]);
        __builtin_amdgcn_s_setprio(1);
#pragma unroll
        for (int mi = 0; mi < 4; ++mi)
#pragma unroll
            for (int ni = 0; ni < 4; ++ni)
                acc[mi][ni] = __builtin_amdgcn_mfma_f32_16x16x32_bf16(
                    a[mi], b[ni], acc[mi][ni], 0, 0, 0);
        __builtin_amdgcn_s_setprio(0);
        if (kt < 31) {                            // write-late into other slot
            float af = alf[(kt + 1) >> 3];
            bf16x8 pw;
#pragma unroll
            for (int j = 0; j < 8; ++j) pw[j] = (bf16)(b2f(p8[j]) * af);
            *reinterpret_cast<bf16x8*>(&ldsA[cur ^ 1][ar * 32 + asw]) = pw;
            *reinterpret_cast<u16x8*>(&ldsB[cur ^ 1][br * 32 + bsw0]) = v0;
            *reinterpret_cast<u16x8*>(&ldsB[cur ^ 1][br * 32 + bsw1]) = v1;
        }
        __syncthreads();
    }

    bf16* Oj = O + (size_t)job * 524288;
#pragma unroll
    for (int mi = 0; mi < 4; ++mi) {
#pragma unroll
        for (int r = 0; r < 4; ++r) {
            int lr = wm * 64 + mi * 16 + nib * 4 + r;
            float linv = 1.0f / Ll[lr];
#pragma unroll
            for (int ni = 0; ni < 4; ++ni) {
                int gcol = bcol + wn * 64 + ni * 16 + cc;
                Oj[(size_t)(brow + lr) * 512 + gcol] = (bf16)(acc[mi][ni][r] * linv);
            }
        }
    }
}

extern "C" void kernel_launch(void* const* d_in, const int* in_sizes, int n_in,
                              void* d_out, int out_size, void* d_ws, size_t ws_size,
                              hipStream_t stream)
{
    const float* x   = (const float*)d_in[0];
    const float* y   = (const float*)d_in[1];
    const float* ns  = (const float*)d_in[2];
    const float* nb  = (const float*)d_in[3];
    const float* n1s = (const float*)d_in[4];
    const float* n1b = (const float*)d_in[5];
    const float* wq  = (const float*)d_in[6];
    const float* bq  = (const float*)d_in[7];
    const float* wk  = (const float*)d_in[8];
    const float* bk  = (const float*)d_in[9];
    const float* wv  = (const float*)d_in[10];
    const float* bv  = (const float*)d_in[11];
    const float* wp  = (const float*)d_in[12];
    const float* bp  = (const float*)d_in[13];
    float* out = (float*)d_out;

    char* ws = (char*)d_ws;
    bf16* wbf  = (bf16*)ws;                          // 2 MB weights bf16
    float* bpk = (float*)(ws + 2097152);             // 8 KB biases
    bf16* ynT = (bf16*)(ws + 2105344);               // [b][hw][c]
    bf16* hnT = ynT + 8388608;
    bf16* qT  = hnT + 8388608;
    bf16* kT  = qT  + 8388608;
    bf16* v   = kT  + 8388608;                       // [b][c][hw]
    float* stats = (float*)ynT;                      // ynT dead after q/k conv
    bf16* aoT = qT;                                  // qT dead after QK^T
    bf16* P   = (bf16*)(ws + 2105344 + 5ull * 16777216);   // 32 MB bf16
    float* gnst = (float*)(ws + 2105344 + 5ull * 16777216 + 33554432); // 8KB

    const size_t sBC = (size_t)kHW * kC;
    const float scl = 0.044194173824159216f;         // 512^-0.5

    wconv_kernel<<<1024, 256, 0, stream>>>(wq, wk, wv, wp, bq, bk, bv, bp, wbf, bpk);
    gn_stats<<<1024, 256, 0, stream>>>(x, y, gnst);
    gn_apply<<<2048, 256, 0, stream>>>(x, ns, nb, hnT, y, n1s, n1b, ynT, gnst);

    // q & k convs fused (jobs 0/1): out_T[i][o] = in_T[i][c]·W[o][c] + b[o]
    gemm256<2, false, bf16, false, 2, 64><<<256, 512, 0, stream>>>(
        ynT, 8388608, 512, wbf, 262144, 512, qT, 8388608, 512,
        bpk, 512, nullptr, 0, 1.f, nullptr);
    // v conv per batch: v[o][n] = wv[o][c]·hnT[n][c] + bv[o]
    gemm128<1, false, bf16, 4, 4><<<256, 512, 0, stream>>>(
        wbf + 2 * 262144, 0, 512, hnT, sBC, 512, v, sBC, 1024,
        bpk + 1024, 0, nullptr, 0);
    // QK^T -> P_local bf16 + (M,L) stats per (row, bx)
    gemm256<0, false, bf16, true, 4, 4><<<256, 512, 0, stream>>>(
        qT, sBC, 512, kT, sBC, 512, P, 1048576, 1024,
        bpk, 0, nullptr, 0, scl, stats);
    // fused softmax-finish + PV -> aoT [b][hw][c]
    pv_gemm<<<256, 512, 0, stream>>>(P, stats, v, aoT);
    // proj + bias + residual
    gemm128<1, true, float, 4, 4><<<256, 512, 0, stream>>>(
        wbf + 3 * 262144, 0, 512, aoT, sBC, 512, out, sBC, 1024,
        bpk + 1536, 0, x, sBC);
}

// Round 9
// 144.554 us; speedup vs baseline: 1.0490x; 1.0490x over previous
//
#include <hip/hip_runtime.h>
#include <hip/hip_bf16.h>

typedef __bf16 bf16;
typedef __bf16 bf16x8 __attribute__((ext_vector_type(8)));
typedef __bf16 bf16x4 __attribute__((ext_vector_type(4)));
typedef float f32x4 __attribute__((ext_vector_type(4)));
typedef unsigned short u16;
typedef unsigned short u16x8 __attribute__((ext_vector_type(8)));

constexpr int kHW = 1024;
constexpr int kC  = 512;

__device__ inline float wave_sum(float v) {
#pragma unroll
    for (int o = 32; o; o >>= 1) v += __shfl_xor(v, o, 64);
    return v;
}

__device__ inline float b2f(u16 u) {
    union { float f; unsigned i; } z; z.i = ((unsigned)u) << 16; return z.f;
}

__device__ inline void gload_lds16(const void* g, void* l) {
    __builtin_amdgcn_global_load_lds(
        (const __attribute__((address_space(1))) void*)g,
        (__attribute__((address_space(3))) void*)l, 16, 0, 0);
}

#define VMCNT(n) asm volatile("s_waitcnt vmcnt(" #n ")" ::: "memory")
#define SBAR __builtin_amdgcn_s_barrier()
#define NOP do {} while (0)

// ===== fused: GroupNorm(x)->hnT, GroupNorm(y)->ynT, weights f32->bf16 =====
// blocks 0..1023: GN (sel = bid>>9, 512 blocks per tensor, one per (b,g)).
//   Raw x staged as bf16 in 33KB LDS (4 blocks/CU); stats in f32 from the
//   f32 stream; pass-2 reads LDS, writes transposed bf16x4 (32B/4 lanes).
// blocks 1024..2047: weight convert + bias pack (latency-bound filler).
__global__ __launch_bounds__(256) void gn2w_kernel(
    const float* __restrict__ x0, const float* __restrict__ s0,
    const float* __restrict__ b0, bf16* __restrict__ o0,
    const float* __restrict__ x1, const float* __restrict__ s1,
    const float* __restrict__ b1, bf16* __restrict__ o1,
    const float* __restrict__ wq, const float* __restrict__ wk,
    const float* __restrict__ wv, const float* __restrict__ wp,
    const float* __restrict__ bq, const float* __restrict__ bk,
    const float* __restrict__ bv, const float* __restrict__ bp,
    bf16* __restrict__ wdst, float* __restrict__ bpk)
{
    int bid = blockIdx.x;
    int t = threadIdx.x;
    if (bid >= 1024) {                    // weight-pack blocks
        int i = (bid - 1024) * 256 + t;
        wdst[i]            = (bf16)wq[i];
        wdst[262144 + i]   = (bf16)wk[i];
        wdst[2*262144 + i] = (bf16)wv[i];
        wdst[3*262144 + i] = (bf16)wp[i];
        if (i < 2048) {
            int j = i >> 9, c = i & 511;
            const float* s = j == 0 ? bq : j == 1 ? bk : j == 2 ? bv : bp;
            bpk[i] = s[c];
        }
        return;
    }

    __shared__ u16 xs[16][1032];          // raw bf16 tile, 33KB
    __shared__ float red[8];
    __shared__ float ab[2][16];

    int sel = bid >> 9;
    int blk = bid & 511;
    const float* x = sel ? x1 : x0;
    const float* scale = sel ? s1 : s0;
    const float* bias  = sel ? b1 : b0;
    bf16* outT = sel ? o1 : o0;

    int b = blk >> 5, g = blk & 31;
    int c0 = g * 16;
    const float* xg = x + ((size_t)b * kC + c0) * kHW;

    float s = 0.f, s2 = 0.f;
    const float4* xg4 = reinterpret_cast<const float4*>(xg);
#pragma unroll
    for (int i = 0; i < 16; ++i) {
        float4 v = xg4[t + i * 256];      // channel i, col 4t
        bf16x4 r;
        r[0] = (bf16)v.x; r[1] = (bf16)v.y; r[2] = (bf16)v.z; r[3] = (bf16)v.w;
        *reinterpret_cast<bf16x4*>(&xs[i][t * 4]) = r;
        s  += v.x + v.y + v.z + v.w;
        s2 += v.x*v.x + v.y*v.y + v.z*v.z + v.w*v.w;
    }
    s = wave_sum(s); s2 = wave_sum(s2);
    int lane = t & 63, wid = t >> 6;
    if (!lane) { red[wid] = s; red[4 + wid] = s2; }
    __syncthreads();
    float ts = red[0] + red[1] + red[2] + red[3];
    float t2 = red[4] + red[5] + red[6] + red[7];
    float mean = ts * (1.f / 16384.f);
    float var  = t2 * (1.f / 16384.f) - mean * mean;
    float inv  = rsqrtf(var + 1e-6f);

    if (t < 16) {
        float a = inv * scale[c0 + t];
        ab[0][t] = a;
        ab[1][t] = bias[c0 + t] - mean * a;
    }
    __syncthreads();

    int cg = t & 3, spw = t >> 2;         // 4 channel-groups x 64 rows
    float a0 = ab[0][cg*4],   a1 = ab[0][cg*4+1],
          a2 = ab[0][cg*4+2], a3 = ab[0][cg*4+3];
    float d0 = ab[1][cg*4],   d1 = ab[1][cg*4+1],
          d2 = ab[1][cg*4+2], d3 = ab[1][cg*4+3];
    bf16* ob = outT + (size_t)b * kHW * kC + c0 + cg * 4;
#pragma unroll
    for (int i = 0; i < 16; ++i) {
        int sp = spw + i * 64;
        bf16x4 w;
        w[0] = (bf16)(b2f(xs[cg*4 + 0][sp]) * a0 + d0);
        w[1] = (bf16)(b2f(xs[cg*4 + 1][sp]) * a1 + d1);
        w[2] = (bf16)(b2f(xs[cg*4 + 2][sp]) * a2 + d2);
        w[3] = (bf16)(b2f(xs[cg*4 + 3][sp]) * a3 + d3);
        *reinterpret_cast<bf16x4*>(ob + (size_t)sp * kC) = w;
    }
}

// ======== 256x256 8-phase NT GEMM, K=512. Schedule v2 =====================
template <int BIAS, bool RESID, typename OUT_T, bool STATS, int NBX, int NBY>
__global__ __launch_bounds__(512, 2) void gemm256(
    const bf16* __restrict__ Ab, size_t sA, int lda,
    const bf16* __restrict__ Bb, size_t sB, int ldb,
    OUT_T* __restrict__ Cb, size_t sC, int ldc,
    const float* __restrict__ biasB, int sBias,
    const float* __restrict__ residB, size_t sR,
    float alpha, float* __restrict__ statsOut)
{
    __shared__ u16 lds[65536];           // 128KB: A 8x8KB (2slot x 4q), B same
    constexpr int NT = 8;                // K = 512

    int bid = blockIdx.x, nwg = gridDim.x;
    int swz = (bid & 7) * (nwg >> 3) + (bid >> 3);
    int job = swz / (NBX * NBY), rem = swz % (NBX * NBY);
    int by = rem / NBX, bx = rem % NBX;
    int brow = by * 256, bcol = bx * 256;

    const u16* Au = reinterpret_cast<const u16*>(Ab + (size_t)job * sA);
    const u16* Bu = reinterpret_cast<const u16*>(Bb + (size_t)job * sB);

    int t = threadIdx.x;
    int lane = t & 63, w = t >> 6;
    int wm = w >> 2, wn = w & 3;
    int cc = lane & 15, nib = lane >> 4;

    int trow = t >> 3;                               // 0..63
    int gsrc = ((t & 7) ^ (trow & 7)) * 8;           // pre-swizzled src granule
    const u16* Asrc = Au + (size_t)(brow + trow) * lda + gsrc;
    const u16* Bsrc = Bu + (size_t)(bcol + trow) * ldb + gsrc;
    u16* LDSA = lds;
    u16* LDSB = lds + 32768;

#define STAGE_A(TL, Q) gload_lds16(Asrc + (size_t)(Q) * 64 * lda + (TL) * 64, \
                                   LDSA + (((TL)&1)*4 + (Q)) * 4096 + t * 8)
#define STAGE_B(TL, Q) gload_lds16(Bsrc + (size_t)(Q) * 64 * ldb + (TL) * 64, \
                                   LDSB + (((TL)&1)*4 + (Q)) * 4096 + t * 8)

    f32x4 acc[8][4] = {};
    bf16x8 afr[4][2], bfr[4][2];

#define PHASE(MH, NH, TL, STG, WTC)                                           \
  {                                                                           \
    if ((NH) == 0) {                                                          \
      _Pragma("unroll") for (int mi = 0; mi < 4; ++mi)                        \
      _Pragma("unroll") for (int kx = 0; kx < 2; ++kx)                        \
        afr[mi][kx] = *reinterpret_cast<const bf16x8*>(LDSA +                 \
            (((TL)&1)*4 + wm*2 + (MH)) * 4096 + (mi*16 + cc) * 64 +           \
            (((nib + kx*4) ^ (cc & 7)) * 8));                                 \
    }                                                                         \
    if ((MH) == 0) {                                                          \
      _Pragma("unroll") for (int ni = 0; ni < 2; ++ni)                        \
      _Pragma("unroll") for (int kx = 0; kx < 2; ++kx)                        \
        bfr[(NH)*2 + ni][kx] = *reinterpret_cast<const bf16x8*>(LDSB +        \
            (((TL)&1)*4 + wn) * 4096 + (((NH)*2 + ni)*16 + cc) * 64 +         \
            (((nib + kx*4) ^ (cc & 7)) * 8));                                 \
    }                                                                         \
    STG;                                                                      \
    SBAR;                                                                     \
    __builtin_amdgcn_s_setprio(1);                                            \
    _Pragma("unroll") for (int mi = 0; mi < 4; ++mi)                          \
    _Pragma("unroll") for (int ni = 0; ni < 2; ++ni)                          \
    _Pragma("unroll") for (int kx = 0; kx < 2; ++kx)                          \
      acc[(MH)*4 + mi][(NH)*2 + ni] = __builtin_amdgcn_mfma_f32_16x16x32_bf16(\
          afr[mi][kx], bfr[(NH)*2 + ni][kx], acc[(MH)*4 + mi][(NH)*2 + ni],   \
          0, 0, 0);                                                           \
    __builtin_amdgcn_s_setprio(0);                                            \
    WTC;                                                                      \
    SBAR;                                                                     \
  }

    // prologue: tiles 0 and 1 fully staged; wait for tile 0
    STAGE_A(0, 0); STAGE_A(0, 2); STAGE_B(0, 0); STAGE_B(0, 1);
    STAGE_B(0, 2); STAGE_B(0, 3); STAGE_A(0, 1); STAGE_A(0, 3);
    STAGE_A(1, 0); STAGE_A(1, 2); STAGE_B(1, 0); STAGE_B(1, 1);
    STAGE_B(1, 2); STAGE_B(1, 3); STAGE_A(1, 1); STAGE_A(1, 3);
    VMCNT(8);
    SBAR;

#pragma unroll
    for (int kt = 0; kt < NT; ++kt) {
        PHASE(0, 0, kt, NOP, NOP);
        PHASE(0, 1, kt,
              if (kt + 2 < NT) { STAGE_A(kt + 2, 0); STAGE_A(kt + 2, 2); },
              NOP);
        PHASE(1, 0, kt,
              if (kt + 2 < NT) { STAGE_B(kt + 2, 0); STAGE_B(kt + 2, 1); },
              NOP);
        PHASE(1, 1, kt,
              if (kt + 2 < NT) { STAGE_B(kt + 2, 2); STAGE_B(kt + 2, 3);
                                 STAGE_A(kt + 2, 1); STAGE_A(kt + 2, 3); },
              if (kt < NT - 2) { VMCNT(8); } else if (kt == NT - 2) { VMCNT(0); });
    }
#undef PHASE
#undef STAGE_A
#undef STAGE_B

#pragma unroll
    for (int m = 0; m < 8; ++m)
#pragma unroll
        for (int n = 0; n < 4; ++n)
#pragma unroll
            for (int r = 0; r < 4; ++r)
                acc[m][n][r] *= alpha;

    if constexpr (STATS) {
        float* sredM = reinterpret_cast<float*>(lds);          // [4][256]
        float* sredS = reinterpret_cast<float*>(lds) + 1024;   // [4][256]
        float rmax[8][4];
#pragma unroll
        for (int m = 0; m < 8; ++m)
#pragma unroll
            for (int r = 0; r < 4; ++r) {
                float v_ = fmaxf(fmaxf(acc[m][0][r], acc[m][1][r]),
                                 fmaxf(acc[m][2][r], acc[m][3][r]));
                v_ = fmaxf(v_, __shfl_xor(v_, 1, 64));
                v_ = fmaxf(v_, __shfl_xor(v_, 2, 64));
                v_ = fmaxf(v_, __shfl_xor(v_, 4, 64));
                v_ = fmaxf(v_, __shfl_xor(v_, 8, 64));
                rmax[m][r] = v_;
            }
        if (cc == 0)
#pragma unroll
            for (int m = 0; m < 8; ++m)
#pragma unroll
                for (int r = 0; r < 4; ++r)
                    sredM[wn * 256 + wm * 128 + m * 16 + nib * 4 + r] = rmax[m][r];
        __syncthreads();
#pragma unroll
        for (int m = 0; m < 8; ++m)
#pragma unroll
            for (int r = 0; r < 4; ++r) {
                int lr = wm * 128 + m * 16 + nib * 4 + r;
                rmax[m][r] = fmaxf(fmaxf(sredM[lr], sredM[256 + lr]),
                                   fmaxf(sredM[512 + lr], sredM[768 + lr]));
            }
#pragma unroll
        for (int m = 0; m < 8; ++m)
#pragma unroll
            for (int r = 0; r < 4; ++r) {
                float s_ = 0.f;
#pragma unroll
                for (int n = 0; n < 4; ++n) {
                    float e = __expf(acc[m][n][r] - rmax[m][r]);
                    acc[m][n][r] = e;
                    s_ += e;
                }
                s_ += __shfl_xor(s_, 1, 64);
                s_ += __shfl_xor(s_, 2, 64);
                s_ += __shfl_xor(s_, 4, 64);
                s_ += __shfl_xor(s_, 8, 64);
                if (cc == 0)
                    sredS[wn * 256 + wm * 128 + m * 16 + nib * 4 + r] = s_;
            }
        __syncthreads();
        if (t < 256) {
            float M = fmaxf(fmaxf(sredM[t], sredM[256 + t]),
                            fmaxf(sredM[512 + t], sredM[768 + t]));
            float L = sredS[t] + sredS[256 + t] + sredS[512 + t] + sredS[768 + t];
            size_t off = ((size_t)(job * 1024 + brow + t)) * 8 + bx * 2;
            statsOut[off]     = M;
            statsOut[off + 1] = L;
        }
    }

    OUT_T* Cj = Cb + (size_t)job * sC;
    const float* bias = biasB + (size_t)job * sBias;
#pragma unroll
    for (int m = 0; m < 8; ++m) {
#pragma unroll
        for (int n = 0; n < 4; ++n) {
#pragma unroll
            for (int r = 0; r < 4; ++r) {
                int grow = brow + wm * 128 + m * 16 + nib * 4 + r;
                int gcol = bcol + wn * 64 + n * 16 + cc;
                float vv = acc[m][n][r];
                if (BIAS == 1) vv += bias[grow];
                if (BIAS == 2) vv += bias[gcol];
                if (RESID)     vv += residB[(size_t)job * sR + (size_t)grow * ldc + gcol];
                Cj[(size_t)grow * ldc + gcol] = (OUT_T)vv;
            }
        }
    }
}

// ======== 128x256 NT GEMM, BK=64, ring-3 slots, 1 barrier/tile ============
template <int BIAS, bool RESID, typename OUT_T, int NBX, int NBY>
__global__ __launch_bounds__(512, 2) void gemm128(
    const bf16* __restrict__ Ab, size_t sA, int lda,
    const bf16* __restrict__ Bb, size_t sB, int ldb,
    OUT_T* __restrict__ Cb, size_t sC, int ldc,
    const float* __restrict__ biasB, int sBias,
    const float* __restrict__ residB, size_t sR)
{
    __shared__ u16 lds[3 * 24576];       // 144KB: 3 slots x (A 16KB + B 32KB)
    constexpr int NT = 8;

    int bid = blockIdx.x, nwg = gridDim.x;
    int swz = (bid & 7) * (nwg >> 3) + (bid >> 3);
    int job = swz / (NBX * NBY), rem = swz % (NBX * NBY);
    int by = rem / NBX, bx = rem % NBX;
    int brow = by * 128, bcol = bx * 256;

    const u16* Au = reinterpret_cast<const u16*>(Ab + (size_t)job * sA);
    const u16* Bu = reinterpret_cast<const u16*>(Bb + (size_t)job * sB);

    int t = threadIdx.x;
    int lane = t & 63, w = t >> 6;
    int wm = w >> 2, wn = w & 3;         // wm 0..1 (M), wn 0..3 (N)
    int cc = lane & 15, nib = lane >> 4;

    int trow = t >> 3;
    int gsrc = ((t & 7) ^ (trow & 7)) * 8;
    const u16* Asrc = Au + (size_t)(brow + trow) * lda + gsrc;
    const u16* Bsrc = Bu + (size_t)(bcol + trow) * ldb + gsrc;

#define STG_T(TL) {                                                           \
    u16* sl_ = lds + ((TL) % 3) * 24576;                                      \
    gload_lds16(Asrc + (TL) * 64,                          sl_ + t * 8);      \
    gload_lds16(Asrc + (size_t)64 * lda + (TL) * 64,       sl_ + 4096 + t*8); \
    gload_lds16(Bsrc + (TL) * 64,                          sl_ + 8192 + t*8); \
    gload_lds16(Bsrc + (size_t)64  * ldb + (TL) * 64,      sl_ + 12288 + t*8);\
    gload_lds16(Bsrc + (size_t)128 * ldb + (TL) * 64,      sl_ + 16384 + t*8);\
    gload_lds16(Bsrc + (size_t)192 * ldb + (TL) * 64,      sl_ + 20480 + t*8);\
  }

    f32x4 acc[4][4] = {};

    STG_T(0); STG_T(1);
    VMCNT(6);
    SBAR;

#pragma unroll
    for (int kt = 0; kt < NT; ++kt) {
        if (kt + 2 < NT) STG_T(kt + 2);
        const u16* sb = lds + (kt % 3) * 24576;
        bf16x8 a[4][2], b[4][2];
#pragma unroll
        for (int mi = 0; mi < 4; ++mi)
#pragma unroll
            for (int kx = 0; kx < 2; ++kx)
                a[mi][kx] = *reinterpret_cast<const bf16x8*>(sb +
                    wm * 4096 + (mi*16 + cc) * 64 + (((nib + kx*4) ^ (cc & 7)) * 8));
#pragma unroll
        for (int ni = 0; ni < 4; ++ni)
#pragma unroll
            for (int kx = 0; kx < 2; ++kx)
                b[ni][kx] = *reinterpret_cast<const bf16x8*>(sb + 8192 +
                    wn * 4096 + (ni*16 + cc) * 64 + (((nib + kx*4) ^ (cc & 7)) * 8));
        __builtin_amdgcn_s_setprio(1);
#pragma unroll
        for (int mi = 0; mi < 4; ++mi)
#pragma unroll
            for (int ni = 0; ni < 4; ++ni)
#pragma unroll
                for (int kx = 0; kx < 2; ++kx)
                    acc[mi][ni] = __builtin_amdgcn_mfma_f32_16x16x32_bf16(
                        a[mi][kx], b[ni][kx], acc[mi][ni], 0, 0, 0);
        __builtin_amdgcn_s_setprio(0);
        if (kt < NT - 2) { VMCNT(6); } else if (kt == NT - 2) { VMCNT(0); }
        SBAR;
    }
#undef STG_T

    OUT_T* Cj = Cb + (size_t)job * sC;
    const float* bias = biasB + (size_t)job * sBias;
#pragma unroll
    for (int mi = 0; mi < 4; ++mi) {
#pragma unroll
        for (int ni = 0; ni < 4; ++ni) {
#pragma unroll
            for (int r = 0; r < 4; ++r) {
                int grow = brow + wm * 64 + mi * 16 + nib * 4 + r;
                int gcol = bcol + wn * 64 + ni * 16 + cc;
                float vv = acc[mi][ni][r];
                if (BIAS == 1) vv += bias[grow];
                if (BIAS == 2) vv += bias[gcol];
                if (RESID)     vv += residB[(size_t)job * sR + (size_t)grow * ldc + gcol];
                Cj[(size_t)grow * ldc + gcol] = (OUT_T)vv;
            }
        }
    }
}

// ======== PV: O = (P_local * alpha_blk) . V^T / L ==========================
__global__ __launch_bounds__(512, 2) void pv_gemm(
    const bf16* __restrict__ P, const float* __restrict__ stats,
    const bf16* __restrict__ V, bf16* __restrict__ O)
{
    __shared__ u16 ldsA[2][4096];        // 128 x 32
    __shared__ u16 ldsB[2][8192];        // 256 x 32
    __shared__ float Ml[128], Ll[128], Mb[4][128];

    int bid = blockIdx.x;
    int swz = (bid & 7) * 32 + (bid >> 3);       // nwg = 256
    int job = swz >> 4, rem = swz & 15;
    int by = rem >> 1, bx = rem & 1;             // 8 x 2 tiles
    int brow = by * 128, bcol = bx * 256;

    int t = threadIdx.x;
    int lane = t & 63, w = t >> 6;
    int wm = w >> 2, wn = w & 3;
    int cc = lane & 15, nib = lane >> 4;

    if (t < 128) {
        const float* st = stats + ((size_t)(job * 1024 + brow + t)) * 8;
        float M = st[0];
#pragma unroll
        for (int k = 1; k < 4; ++k) M = fmaxf(M, st[2 * k]);
        float L = 0.f;
#pragma unroll
        for (int k = 0; k < 4; ++k) L += st[2 * k + 1] * __expf(st[2 * k] - M);
        Ml[t] = M; Ll[t] = L;
        Mb[0][t] = st[0]; Mb[1][t] = st[2]; Mb[2][t] = st[4]; Mb[3][t] = st[6];
    }
    __syncthreads();

    int ar = t >> 2, ag = t & 3;                 // A: row, col-group
    int asw = ((ag ^ ((ar >> 1) & 3))) * 8;      // swizzled write col
    float alf[4];
#pragma unroll
    for (int k = 0; k < 4; ++k) alf[k] = __expf(Mb[k][ar] - Ml[ar]);

    const u16* Pr = reinterpret_cast<const u16*>(P) + (size_t)job * 1048576
                    + (size_t)(brow + ar) * 1024 + ag * 8;
    int br = t >> 1;
    const u16* Vr = reinterpret_cast<const u16*>(V) + (size_t)job * 524288
                    + (size_t)(bcol + br) * 1024 + (t & 1) * 16;
    int bg0 = (t & 1) * 2, bg1 = bg0 + 1;
    int bsw0 = (bg0 ^ ((br >> 1) & 3)) * 8;
    int bsw1 = (bg1 ^ ((br >> 1) & 3)) * 8;
    int rsw = (nib ^ ((cc >> 1) & 3)) * 8;       // swizzled read col

    f32x4 acc[4][4] = {};

    {
        u16x8 p8 = *reinterpret_cast<const u16x8*>(Pr);
        u16x8 v0 = *reinterpret_cast<const u16x8*>(Vr);
        u16x8 v1 = *reinterpret_cast<const u16x8*>(Vr + 8);
        float af = alf[0];
        bf16x8 pw;
#pragma unroll
        for (int j = 0; j < 8; ++j) pw[j] = (bf16)(b2f(p8[j]) * af);
        *reinterpret_cast<bf16x8*>(&ldsA[0][ar * 32 + asw]) = pw;
        *reinterpret_cast<u16x8*>(&ldsB[0][br * 32 + bsw0]) = v0;
        *reinterpret_cast<u16x8*>(&ldsB[0][br * 32 + bsw1]) = v1;
    }
    __syncthreads();

#pragma unroll
    for (int kt = 0; kt < 32; ++kt) {
        int cur = kt & 1;
        u16x8 p8, v0, v1;
        if (kt < 31) {                            // T14: issue loads early
            p8 = *reinterpret_cast<const u16x8*>(Pr + (kt + 1) * 32);
            v0 = *reinterpret_cast<const u16x8*>(Vr + (kt + 1) * 32);
            v1 = *reinterpret_cast<const u16x8*>(Vr + (kt + 1) * 32 + 8);
        }
        bf16x8 a[4], b[4];
#pragma unroll
        for (int mi = 0; mi < 4; ++mi)
            a[mi] = *reinterpret_cast<const bf16x8*>(
                &ldsA[cur][(wm * 64 + mi * 16 + cc) * 32 + rsw]);
#pragma unroll
        for (int ni = 0; ni < 4; ++ni)
            b[ni] = *reinterpret_cast<const bf16x8*>(
                &ldsB[cur][(wn * 64 + ni * 16 + cc) * 32 + rsw]);
        __builtin_amdgcn_s_setprio(1);
#pragma unroll
        for (int mi = 0; mi < 4; ++mi)
#pragma unroll
            for (int ni = 0; ni < 4; ++ni)
                acc[mi][ni] = __builtin_amdgcn_mfma_f32_16x16x32_bf16(
                    a[mi], b[ni], acc[mi][ni], 0, 0, 0);
        __builtin_amdgcn_s_setprio(0);
        if (kt < 31) {                            // write-late into other slot
            float af = alf[(kt + 1) >> 3];
            bf16x8 pw;
#pragma unroll
            for (int j = 0; j < 8; ++j) pw[j] = (bf16)(b2f(p8[j]) * af);
            *reinterpret_cast<bf16x8*>(&ldsA[cur ^ 1][ar * 32 + asw]) = pw;
            *reinterpret_cast<u16x8*>(&ldsB[cur ^ 1][br * 32 + bsw0]) = v0;
            *reinterpret_cast<u16x8*>(&ldsB[cur ^ 1][br * 32 + bsw1]) = v1;
        }
        __syncthreads();
    }

    bf16* Oj = O + (size_t)job * 524288;
#pragma unroll
    for (int mi = 0; mi < 4; ++mi) {
#pragma unroll
        for (int r = 0; r < 4; ++r) {
            int lr = wm * 64 + mi * 16 + nib * 4 + r;
            float linv = 1.0f / Ll[lr];
#pragma unroll
            for (int ni = 0; ni < 4; ++ni) {
                int gcol = bcol + wn * 64 + ni * 16 + cc;
                Oj[(size_t)(brow + lr) * 512 + gcol] = (bf16)(acc[mi][ni][r] * linv);
            }
        }
    }
}

extern "C" void kernel_launch(void* const* d_in, const int* in_sizes, int n_in,
                              void* d_out, int out_size, void* d_ws, size_t ws_size,
                              hipStream_t stream)
{
    const float* x   = (const float*)d_in[0];
    const float* y   = (const float*)d_in[1];
    const float* ns  = (const float*)d_in[2];
    const float* nb  = (const float*)d_in[3];
    const float* n1s = (const float*)d_in[4];
    const float* n1b = (const float*)d_in[5];
    const float* wq  = (const float*)d_in[6];
    const float* bq  = (const float*)d_in[7];
    const float* wk  = (const float*)d_in[8];
    const float* bk  = (const float*)d_in[9];
    const float* wv  = (const float*)d_in[10];
    const float* bv  = (const float*)d_in[11];
    const float* wp  = (const float*)d_in[12];
    const float* bp  = (const float*)d_in[13];
    float* out = (float*)d_out;

    char* ws = (char*)d_ws;
    bf16* wbf  = (bf16*)ws;                          // 2 MB weights bf16
    float* bpk = (float*)(ws + 2097152);             // 8 KB biases
    bf16* ynT = (bf16*)(ws + 2105344);               // [b][hw][c]
    bf16* hnT = ynT + 8388608;
    bf16* qT  = hnT + 8388608;
    bf16* kT  = qT  + 8388608;
    bf16* v   = kT  + 8388608;                       // [b][c][hw]
    float* stats = (float*)ynT;                      // ynT dead after q/k conv
    bf16* aoT = qT;                                  // qT dead after QK^T
    bf16* P   = (bf16*)(ws + 2105344 + 5ull * 16777216);   // 32 MB bf16

    const size_t sBC = (size_t)kHW * kC;
    const float scl = 0.044194173824159216f;         // 512^-0.5

    // GN(x)->hnT, GN(y)->ynT, weight pack — one launch
    gn2w_kernel<<<2048, 256, 0, stream>>>(
        x, ns, nb, hnT, y, n1s, n1b, ynT,
        wq, wk, wv, wp, bq, bk, bv, bp, wbf, bpk);

    // q & k convs fused (jobs 0/1): out_T[i][o] = in_T[i][c]·W[o][c] + b[o]
    gemm256<2, false, bf16, false, 2, 64><<<256, 512, 0, stream>>>(
        ynT, 8388608, 512, wbf, 262144, 512, qT, 8388608, 512,
        bpk, 512, nullptr, 0, 1.f, nullptr);
    // v conv per batch: v[o][n] = wv[o][c]·hnT[n][c] + bv[o]
    gemm128<1, false, bf16, 4, 4><<<256, 512, 0, stream>>>(
        wbf + 2 * 262144, 0, 512, hnT, sBC, 512, v, sBC, 1024,
        bpk + 1024, 0, nullptr, 0);
    // QK^T -> P_local bf16 + (M,L) stats per (row, bx)
    gemm256<0, false, bf16, true, 4, 4><<<256, 512, 0, stream>>>(
        qT, sBC, 512, kT, sBC, 512, P, 1048576, 1024,
        bpk, 0, nullptr, 0, scl, stats);
    // fused softmax-finish + PV -> aoT [b][hw][c]
    pv_gemm<<<256, 512, 0, stream>>>(P, stats, v, aoT);
    // proj + bias + residual
    gemm128<1, true, float, 4, 4><<<256, 512, 0, stream>>>(
        wbf + 3 * 262144, 0, 512, aoT, sBC, 512, out, sBC, 1024,
        bpk + 1536, 0, x, sBC);
}

// Round 10
// 139.380 us; speedup vs baseline: 1.0879x; 1.0371x over previous
//
#include <hip/hip_runtime.h>
#include <hip/hip_bf16.h>

typedef __bf16 bf16;
typedef __bf16 bf16x8 __attribute__((ext_vector_type(8)));
typedef __bf16 bf16x4 __attribute__((ext_vector_type(4)));
typedef float f32x4 __attribute__((ext_vector_type(4)));
typedef unsigned short u16;
typedef unsigned short u16x8 __attribute__((ext_vector_type(8)));

constexpr int kHW = 1024;
constexpr int kC  = 512;

__device__ inline float wave_sum(float v) {
#pragma unroll
    for (int o = 32; o; o >>= 1) v += __shfl_xor(v, o, 64);
    return v;
}

__device__ inline float b2f(u16 u) {
    union { float f; unsigned i; } z; z.i = ((unsigned)u) << 16; return z.f;
}

__device__ inline void gload_lds16(const void* g, void* l) {
    __builtin_amdgcn_global_load_lds(
        (const __attribute__((address_space(1))) void*)g,
        (__attribute__((address_space(3))) void*)l, 16, 0, 0);
}

#define VMCNT(n) asm volatile("s_waitcnt vmcnt(" #n ")" ::: "memory")
#define SBAR __builtin_amdgcn_s_barrier()
#define NOP do {} while (0)

// ===== fused: GroupNorm(x)->hnT, GroupNorm(y)->ynT, weights f32->bf16 =====
// GN blocks (0..1023): XCD-locality swizzle — all 32 group-blocks of one
// (tensor,batch) land on ONE XCD (dispatch round-robins bid across XCDs),
// so their 32B output-row fragments merge in that XCD's L2 into full
// 128B lines (kills partial-line RMW at HBM).
// blocks 1024..2047: weight convert + bias pack (latency filler).
__global__ __launch_bounds__(256) void gn2w_kernel(
    const float* __restrict__ x0, const float* __restrict__ s0,
    const float* __restrict__ b0, bf16* __restrict__ o0,
    const float* __restrict__ x1, const float* __restrict__ s1,
    const float* __restrict__ b1, bf16* __restrict__ o1,
    const float* __restrict__ wq, const float* __restrict__ wk,
    const float* __restrict__ wv, const float* __restrict__ wp,
    const float* __restrict__ bq, const float* __restrict__ bk,
    const float* __restrict__ bv, const float* __restrict__ bp,
    bf16* __restrict__ wdst, float* __restrict__ bpk)
{
    int bid = blockIdx.x;
    int t = threadIdx.x;
    if (bid >= 1024) {                    // weight-pack blocks
        int i = (bid - 1024) * 256 + t;
        wdst[i]            = (bf16)wq[i];
        wdst[262144 + i]   = (bf16)wk[i];
        wdst[2*262144 + i] = (bf16)wv[i];
        wdst[3*262144 + i] = (bf16)wp[i];
        if (i < 2048) {
            int j = i >> 9, c = i & 511;
            const float* s = j == 0 ? bq : j == 1 ? bk : j == 2 ? bv : bp;
            bpk[i] = s[c];
        }
        return;
    }

    __shared__ u16 xs[16][1032];          // raw bf16 tile, 33KB
    __shared__ float red[8];
    __shared__ float ab[2][16];

    // XCD-locality decode: xcd = bid&7 owns 4 (sel,b) pairs, each with all 32 g
    int xcd = bid & 7, idx = bid >> 3;    // idx 0..127
    int pair = xcd * 4 + (idx >> 5);      // 0..31
    int g = idx & 31;
    int sel = pair >> 4;
    int b = pair & 15;

    const float* x = sel ? x1 : x0;
    const float* scale = sel ? s1 : s0;
    const float* bias  = sel ? b1 : b0;
    bf16* outT = sel ? o1 : o0;

    int c0 = g * 16;
    const float* xg = x + ((size_t)b * kC + c0) * kHW;

    float s = 0.f, s2 = 0.f;
    const float4* xg4 = reinterpret_cast<const float4*>(xg);
#pragma unroll
    for (int i = 0; i < 16; ++i) {
        float4 v = xg4[t + i * 256];      // channel i, col 4t
        bf16x4 r;
        r[0] = (bf16)v.x; r[1] = (bf16)v.y; r[2] = (bf16)v.z; r[3] = (bf16)v.w;
        *reinterpret_cast<bf16x4*>(&xs[i][t * 4]) = r;
        s  += v.x + v.y + v.z + v.w;
        s2 += v.x*v.x + v.y*v.y + v.z*v.z + v.w*v.w;
    }
    s = wave_sum(s); s2 = wave_sum(s2);
    int lane = t & 63, wid = t >> 6;
    if (!lane) { red[wid] = s; red[4 + wid] = s2; }
    __syncthreads();
    float ts = red[0] + red[1] + red[2] + red[3];
    float t2 = red[4] + red[5] + red[6] + red[7];
    float mean = ts * (1.f / 16384.f);
    float var  = t2 * (1.f / 16384.f) - mean * mean;
    float inv  = rsqrtf(var + 1e-6f);

    if (t < 16) {
        float a = inv * scale[c0 + t];
        ab[0][t] = a;
        ab[1][t] = bias[c0 + t] - mean * a;
    }
    __syncthreads();

    int cg = t & 3, spw = t >> 2;         // 4 channel-groups x 64 rows
    float a0 = ab[0][cg*4],   a1 = ab[0][cg*4+1],
          a2 = ab[0][cg*4+2], a3 = ab[0][cg*4+3];
    float d0 = ab[1][cg*4],   d1 = ab[1][cg*4+1],
          d2 = ab[1][cg*4+2], d3 = ab[1][cg*4+3];
    bf16* ob = outT + (size_t)b * kHW * kC + c0 + cg * 4;
#pragma unroll
    for (int i = 0; i < 16; ++i) {
        int sp = spw + i * 64;
        bf16x4 w;
        w[0] = (bf16)(b2f(xs[cg*4 + 0][sp]) * a0 + d0);
        w[1] = (bf16)(b2f(xs[cg*4 + 1][sp]) * a1 + d1);
        w[2] = (bf16)(b2f(xs[cg*4 + 2][sp]) * a2 + d2);
        w[3] = (bf16)(b2f(xs[cg*4 + 3][sp]) * a3 + d3);
        *reinterpret_cast<bf16x4*>(ob + (size_t)sp * kC) = w;
    }
}

// ======== 256x256 8-phase NT GEMM, K=512. Schedule v2 =====================
template <int BIAS, bool RESID, typename OUT_T, bool STATS, int NBX, int NBY>
__global__ __launch_bounds__(512, 2) void gemm256(
    const bf16* __restrict__ Ab, size_t sA, int lda,
    const bf16* __restrict__ Bb, size_t sB, int ldb,
    OUT_T* __restrict__ Cb, size_t sC, int ldc,
    const float* __restrict__ biasB, int sBias,
    const float* __restrict__ residB, size_t sR,
    float alpha, float* __restrict__ statsOut)
{
    __shared__ u16 lds[65536];           // 128KB: A 8x8KB (2slot x 4q), B same
    constexpr int NT = 8;                // K = 512

    int bid = blockIdx.x, nwg = gridDim.x;
    int swz = (bid & 7) * (nwg >> 3) + (bid >> 3);
    int job = swz / (NBX * NBY), rem = swz % (NBX * NBY);
    int by = rem / NBX, bx = rem % NBX;
    int brow = by * 256, bcol = bx * 256;

    const u16* Au = reinterpret_cast<const u16*>(Ab + (size_t)job * sA);
    const u16* Bu = reinterpret_cast<const u16*>(Bb + (size_t)job * sB);

    int t = threadIdx.x;
    int lane = t & 63, w = t >> 6;
    int wm = w >> 2, wn = w & 3;
    int cc = lane & 15, nib = lane >> 4;

    int trow = t >> 3;                               // 0..63
    int gsrc = ((t & 7) ^ (trow & 7)) * 8;           // pre-swizzled src granule
    const u16* Asrc = Au + (size_t)(brow + trow) * lda + gsrc;
    const u16* Bsrc = Bu + (size_t)(bcol + trow) * ldb + gsrc;
    u16* LDSA = lds;
    u16* LDSB = lds + 32768;

#define STAGE_A(TL, Q) gload_lds16(Asrc + (size_t)(Q) * 64 * lda + (TL) * 64, \
                                   LDSA + (((TL)&1)*4 + (Q)) * 4096 + t * 8)
#define STAGE_B(TL, Q) gload_lds16(Bsrc + (size_t)(Q) * 64 * ldb + (TL) * 64, \
                                   LDSB + (((TL)&1)*4 + (Q)) * 4096 + t * 8)

    f32x4 acc[8][4] = {};
    bf16x8 afr[4][2], bfr[4][2];

#define PHASE(MH, NH, TL, STG, WTC)                                           \
  {                                                                           \
    if ((NH) == 0) {                                                          \
      _Pragma("unroll") for (int mi = 0; mi < 4; ++mi)                        \
      _Pragma("unroll") for (int kx = 0; kx < 2; ++kx)                        \
        afr[mi][kx] = *reinterpret_cast<const bf16x8*>(LDSA +                 \
            (((TL)&1)*4 + wm*2 + (MH)) * 4096 + (mi*16 + cc) * 64 +           \
            (((nib + kx*4) ^ (cc & 7)) * 8));                                 \
    }                                                                         \
    if ((MH) == 0) {                                                          \
      _Pragma("unroll") for (int ni = 0; ni < 2; ++ni)                        \
      _Pragma("unroll") for (int kx = 0; kx < 2; ++kx)                        \
        bfr[(NH)*2 + ni][kx] = *reinterpret_cast<const bf16x8*>(LDSB +        \
            (((TL)&1)*4 + wn) * 4096 + (((NH)*2 + ni)*16 + cc) * 64 +         \
            (((nib + kx*4) ^ (cc & 7)) * 8));                                 \
    }                                                                         \
    STG;                                                                      \
    SBAR;                                                                     \
    __builtin_amdgcn_s_setprio(1);                                            \
    _Pragma("unroll") for (int mi = 0; mi < 4; ++mi)                          \
    _Pragma("unroll") for (int ni = 0; ni < 2; ++ni)                          \
    _Pragma("unroll") for (int kx = 0; kx < 2; ++kx)                          \
      acc[(MH)*4 + mi][(NH)*2 + ni] = __builtin_amdgcn_mfma_f32_16x16x32_bf16(\
          afr[mi][kx], bfr[(NH)*2 + ni][kx], acc[(MH)*4 + mi][(NH)*2 + ni],   \
          0, 0, 0);                                                           \
    __builtin_amdgcn_s_setprio(0);                                            \
    WTC;                                                                      \
    SBAR;                                                                     \
  }

    // prologue: tiles 0 and 1 fully staged; wait for tile 0
    STAGE_A(0, 0); STAGE_A(0, 2); STAGE_B(0, 0); STAGE_B(0, 1);
    STAGE_B(0, 2); STAGE_B(0, 3); STAGE_A(0, 1); STAGE_A(0, 3);
    STAGE_A(1, 0); STAGE_A(1, 2); STAGE_B(1, 0); STAGE_B(1, 1);
    STAGE_B(1, 2); STAGE_B(1, 3); STAGE_A(1, 1); STAGE_A(1, 3);
    VMCNT(8);
    SBAR;

#pragma unroll
    for (int kt = 0; kt < NT; ++kt) {
        PHASE(0, 0, kt, NOP, NOP);
        PHASE(0, 1, kt,
              if (kt + 2 < NT) { STAGE_A(kt + 2, 0); STAGE_A(kt + 2, 2); },
              NOP);
        PHASE(1, 0, kt,
              if (kt + 2 < NT) { STAGE_B(kt + 2, 0); STAGE_B(kt + 2, 1); },
              NOP);
        PHASE(1, 1, kt,
              if (kt + 2 < NT) { STAGE_B(kt + 2, 2); STAGE_B(kt + 2, 3);
                                 STAGE_A(kt + 2, 1); STAGE_A(kt + 2, 3); },
              if (kt < NT - 2) { VMCNT(8); } else if (kt == NT - 2) { VMCNT(0); });
    }
#undef PHASE
#undef STAGE_A
#undef STAGE_B

#pragma unroll
    for (int m = 0; m < 8; ++m)
#pragma unroll
        for (int n = 0; n < 4; ++n)
#pragma unroll
            for (int r = 0; r < 4; ++r)
                acc[m][n][r] *= alpha;

    if constexpr (STATS) {
        float* sredM = reinterpret_cast<float*>(lds);          // [4][256]
        float* sredS = reinterpret_cast<float*>(lds) + 1024;   // [4][256]
        float rmax[8][4];
#pragma unroll
        for (int m = 0; m < 8; ++m)
#pragma unroll
            for (int r = 0; r < 4; ++r) {
                float v_ = fmaxf(fmaxf(acc[m][0][r], acc[m][1][r]),
                                 fmaxf(acc[m][2][r], acc[m][3][r]));
                v_ = fmaxf(v_, __shfl_xor(v_, 1, 64));
                v_ = fmaxf(v_, __shfl_xor(v_, 2, 64));
                v_ = fmaxf(v_, __shfl_xor(v_, 4, 64));
                v_ = fmaxf(v_, __shfl_xor(v_, 8, 64));
                rmax[m][r] = v_;
            }
        if (cc == 0)
#pragma unroll
            for (int m = 0; m < 8; ++m)
#pragma unroll
                for (int r = 0; r < 4; ++r)
                    sredM[wn * 256 + wm * 128 + m * 16 + nib * 4 + r] = rmax[m][r];
        __syncthreads();
#pragma unroll
        for (int m = 0; m < 8; ++m)
#pragma unroll
            for (int r = 0; r < 4; ++r) {
                int lr = wm * 128 + m * 16 + nib * 4 + r;
                rmax[m][r] = fmaxf(fmaxf(sredM[lr], sredM[256 + lr]),
                                   fmaxf(sredM[512 + lr], sredM[768 + lr]));
            }
#pragma unroll
        for (int m = 0; m < 8; ++m)
#pragma unroll
            for (int r = 0; r < 4; ++r) {
                float s_ = 0.f;
#pragma unroll
                for (int n = 0; n < 4; ++n) {
                    float e = __expf(acc[m][n][r] - rmax[m][r]);
                    acc[m][n][r] = e;
                    s_ += e;
                }
                s_ += __shfl_xor(s_, 1, 64);
                s_ += __shfl_xor(s_, 2, 64);
                s_ += __shfl_xor(s_, 4, 64);
                s_ += __shfl_xor(s_, 8, 64);
                if (cc == 0)
                    sredS[wn * 256 + wm * 128 + m * 16 + nib * 4 + r] = s_;
            }
        __syncthreads();
        if (t < 256) {
            float M = fmaxf(fmaxf(sredM[t], sredM[256 + t]),
                            fmaxf(sredM[512 + t], sredM[768 + t]));
            float L = sredS[t] + sredS[256 + t] + sredS[512 + t] + sredS[768 + t];
            size_t off = ((size_t)(job * 1024 + brow + t)) * 8 + bx * 2;
            statsOut[off]     = M;
            statsOut[off + 1] = L;
        }
    }

    OUT_T* Cj = Cb + (size_t)job * sC;
    const float* bias = biasB + (size_t)job * sBias;
#pragma unroll
    for (int m = 0; m < 8; ++m) {
#pragma unroll
        for (int n = 0; n < 4; ++n) {
#pragma unroll
            for (int r = 0; r < 4; ++r) {
                int grow = brow + wm * 128 + m * 16 + nib * 4 + r;
                int gcol = bcol + wn * 64 + n * 16 + cc;
                float vv = acc[m][n][r];
                if (BIAS == 1) vv += bias[grow];
                if (BIAS == 2) vv += bias[gcol];
                if (RESID)     vv += residB[(size_t)job * sR + (size_t)grow * ldc + gcol];
                Cj[(size_t)grow * ldc + gcol] = (OUT_T)vv;
            }
        }
    }
}

// ======== 128x256 NT GEMM, BK=64, ring-3 slots, 1 barrier/tile ============
template <int BIAS, bool RESID, typename OUT_T, int NBX, int NBY>
__global__ __launch_bounds__(512, 2) void gemm128(
    const bf16* __restrict__ Ab, size_t sA, int lda,
    const bf16* __restrict__ Bb, size_t sB, int ldb,
    OUT_T* __restrict__ Cb, size_t sC, int ldc,
    const float* __restrict__ biasB, int sBias,
    const float* __restrict__ residB, size_t sR)
{
    __shared__ u16 lds[3 * 24576];       // 144KB: 3 slots x (A 16KB + B 32KB)
    constexpr int NT = 8;

    int bid = blockIdx.x, nwg = gridDim.x;
    int swz = (bid & 7) * (nwg >> 3) + (bid >> 3);
    int job = swz / (NBX * NBY), rem = swz % (NBX * NBY);
    int by = rem / NBX, bx = rem % NBX;
    int brow = by * 128, bcol = bx * 256;

    const u16* Au = reinterpret_cast<const u16*>(Ab + (size_t)job * sA);
    const u16* Bu = reinterpret_cast<const u16*>(Bb + (size_t)job * sB);

    int t = threadIdx.x;
    int lane = t & 63, w = t >> 6;
    int wm = w >> 2, wn = w & 3;         // wm 0..1 (M), wn 0..3 (N)
    int cc = lane & 15, nib = lane >> 4;

    int trow = t >> 3;
    int gsrc = ((t & 7) ^ (trow & 7)) * 8;
    const u16* Asrc = Au + (size_t)(brow + trow) * lda + gsrc;
    const u16* Bsrc = Bu + (size_t)(bcol + trow) * ldb + gsrc;

#define STG_T(TL) {                                                           \
    u16* sl_ = lds + ((TL) % 3) * 24576;                                      \
    gload_lds16(Asrc + (TL) * 64,                          sl_ + t * 8);      \
    gload_lds16(Asrc + (size_t)64 * lda + (TL) * 64,       sl_ + 4096 + t*8); \
    gload_lds16(Bsrc + (TL) * 64,                          sl_ + 8192 + t*8); \
    gload_lds16(Bsrc + (size_t)64  * ldb + (TL) * 64,      sl_ + 12288 + t*8);\
    gload_lds16(Bsrc + (size_t)128 * ldb + (TL) * 64,      sl_ + 16384 + t*8);\
    gload_lds16(Bsrc + (size_t)192 * ldb + (TL) * 64,      sl_ + 20480 + t*8);\
  }

    f32x4 acc[4][4] = {};

    STG_T(0); STG_T(1);
    VMCNT(6);
    SBAR;

#pragma unroll
    for (int kt = 0; kt < NT; ++kt) {
        if (kt + 2 < NT) STG_T(kt + 2);
        const u16* sb = lds + (kt % 3) * 24576;
        bf16x8 a[4][2], b[4][2];
#pragma unroll
        for (int mi = 0; mi < 4; ++mi)
#pragma unroll
            for (int kx = 0; kx < 2; ++kx)
                a[mi][kx] = *reinterpret_cast<const bf16x8*>(sb +
                    wm * 4096 + (mi*16 + cc) * 64 + (((nib + kx*4) ^ (cc & 7)) * 8));
#pragma unroll
        for (int ni = 0; ni < 4; ++ni)
#pragma unroll
            for (int kx = 0; kx < 2; ++kx)
                b[ni][kx] = *reinterpret_cast<const bf16x8*>(sb + 8192 +
                    wn * 4096 + (ni*16 + cc) * 64 + (((nib + kx*4) ^ (cc & 7)) * 8));
        __builtin_amdgcn_s_setprio(1);
#pragma unroll
        for (int mi = 0; mi < 4; ++mi)
#pragma unroll
            for (int ni = 0; ni < 4; ++ni)
#pragma unroll
                for (int kx = 0; kx < 2; ++kx)
                    acc[mi][ni] = __builtin_amdgcn_mfma_f32_16x16x32_bf16(
                        a[mi][kx], b[ni][kx], acc[mi][ni], 0, 0, 0);
        __builtin_amdgcn_s_setprio(0);
        if (kt < NT - 2) { VMCNT(6); } else if (kt == NT - 2) { VMCNT(0); }
        SBAR;
    }
#undef STG_T

    OUT_T* Cj = Cb + (size_t)job * sC;
    const float* bias = biasB + (size_t)job * sBias;
#pragma unroll
    for (int mi = 0; mi < 4; ++mi) {
#pragma unroll
        for (int ni = 0; ni < 4; ++ni) {
#pragma unroll
            for (int r = 0; r < 4; ++r) {
                int grow = brow + wm * 64 + mi * 16 + nib * 4 + r;
                int gcol = bcol + wn * 64 + ni * 16 + cc;
                float vv = acc[mi][ni][r];
                if (BIAS == 1) vv += bias[grow];
                if (BIAS == 2) vv += bias[gcol];
                if (RESID)     vv += residB[(size_t)job * sR + (size_t)grow * ldc + gcol];
                Cj[(size_t)grow * ldc + gcol] = (OUT_T)vv;
            }
        }
    }
}

// ======== PV: O = (P_local * alpha_blk) . V^T / L ==========================
// Single barrier per K-step: reads slot cur, writes slot cur^1 (kt+1);
// same-wave reads drain before the barrier (MFMA dep waits), prior readers
// of cur^1 were sealed by the previous barrier.
__global__ __launch_bounds__(512, 2) void pv_gemm(
    const bf16* __restrict__ P, const float* __restrict__ stats,
    const bf16* __restrict__ V, bf16* __restrict__ O)
{
    __shared__ u16 ldsA[2][4096];        // 128 x 32
    __shared__ u16 ldsB[2][8192];        // 256 x 32
    __shared__ float Ml[128], Ll[128], Mb[4][128];

    int bid = blockIdx.x;
    int swz = (bid & 7) * 32 + (bid >> 3);       // nwg = 256
    int job = swz >> 4, rem = swz & 15;
    int by = rem >> 1, bx = rem & 1;             // 8 x 2 tiles
    int brow = by * 128, bcol = bx * 256;

    int t = threadIdx.x;
    int lane = t & 63, w = t >> 6;
    int wm = w >> 2, wn = w & 3;
    int cc = lane & 15, nib = lane >> 4;

    if (t < 128) {
        const float* st = stats + ((size_t)(job * 1024 + brow + t)) * 8;
        float M = st[0];
#pragma unroll
        for (int k = 1; k < 4; ++k) M = fmaxf(M, st[2 * k]);
        float L = 0.f;
#pragma unroll
        for (int k = 0; k < 4; ++k) L += st[2 * k + 1] * __expf(st[2 * k] - M);
        Ml[t] = M; Ll[t] = L;
        Mb[0][t] = st[0]; Mb[1][t] = st[2]; Mb[2][t] = st[4]; Mb[3][t] = st[6];
    }
    __syncthreads();

    int ar = t >> 2, ag = t & 3;                 // A: row, col-group
    int asw = ((ag ^ ((ar >> 1) & 3))) * 8;      // swizzled write col
    float alf[4];
#pragma unroll
    for (int k = 0; k < 4; ++k) alf[k] = __expf(Mb[k][ar] - Ml[ar]);

    const u16* Pr = reinterpret_cast<const u16*>(P) + (size_t)job * 1048576
                    + (size_t)(brow + ar) * 1024 + ag * 8;
    int br = t >> 1;
    const u16* Vr = reinterpret_cast<const u16*>(V) + (size_t)job * 524288
                    + (size_t)(bcol + br) * 1024 + (t & 1) * 16;
    int bg0 = (t & 1) * 2, bg1 = bg0 + 1;
    int bsw0 = (bg0 ^ ((br >> 1) & 3)) * 8;
    int bsw1 = (bg1 ^ ((br >> 1) & 3)) * 8;
    int rsw = (nib ^ ((cc >> 1) & 3)) * 8;       // swizzled read col

    f32x4 acc[4][4] = {};

    {
        u16x8 p8 = *reinterpret_cast<const u16x8*>(Pr);
        u16x8 v0 = *reinterpret_cast<const u16x8*>(Vr);
        u16x8 v1 = *reinterpret_cast<const u16x8*>(Vr + 8);
        float af = alf[0];
        bf16x8 pw;
#pragma unroll
        for (int j = 0; j < 8; ++j) pw[j] = (bf16)(b2f(p8[j]) * af);
        *reinterpret_cast<bf16x8*>(&ldsA[0][ar * 32 + asw]) = pw;
        *reinterpret_cast<u16x8*>(&ldsB[0][br * 32 + bsw0]) = v0;
        *reinterpret_cast<u16x8*>(&ldsB[0][br * 32 + bsw1]) = v1;
    }
    __syncthreads();

#pragma unroll
    for (int kt = 0; kt < 32; ++kt) {
        int cur = kt & 1;
        u16x8 p8, v0, v1;
        if (kt < 31) {                            // T14: issue loads early
            p8 = *reinterpret_cast<const u16x8*>(Pr + (kt + 1) * 32);
            v0 = *reinterpret_cast<const u16x8*>(Vr + (kt + 1) * 32);
            v1 = *reinterpret_cast<const u16x8*>(Vr + (kt + 1) * 32 + 8);
        }
        bf16x8 a[4], b[4];
#pragma unroll
        for (int mi = 0; mi < 4; ++mi)
            a[mi] = *reinterpret_cast<const bf16x8*>(
                &ldsA[cur][(wm * 64 + mi * 16 + cc) * 32 + rsw]);
#pragma unroll
        for (int ni = 0; ni < 4; ++ni)
            b[ni] = *reinterpret_cast<const bf16x8*>(
                &ldsB[cur][(wn * 64 + ni * 16 + cc) * 32 + rsw]);
        __builtin_amdgcn_s_setprio(1);
#pragma unroll
        for (int mi = 0; mi < 4; ++mi)
#pragma unroll
            for (int ni = 0; ni < 4; ++ni)
                acc[mi][ni] = __builtin_amdgcn_mfma_f32_16x16x32_bf16(
                    a[mi], b[ni], acc[mi][ni], 0, 0, 0);
        __builtin_amdgcn_s_setprio(0);
        if (kt < 31) {                            // write-late into other slot
            float af = alf[(kt + 1) >> 3];
            bf16x8 pw;
#pragma unroll
            for (int j = 0; j < 8; ++j) pw[j] = (bf16)(b2f(p8[j]) * af);
            *reinterpret_cast<bf16x8*>(&ldsA[cur ^ 1][ar * 32 + asw]) = pw;
            *reinterpret_cast<u16x8*>(&ldsB[cur ^ 1][br * 32 + bsw0]) = v0;
            *reinterpret_cast<u16x8*>(&ldsB[cur ^ 1][br * 32 + bsw1]) = v1;
        }
        __syncthreads();                          // single barrier per step
    }

    bf16* Oj = O + (size_t)job * 524288;
#pragma unroll
    for (int mi = 0; mi < 4; ++mi) {
#pragma unroll
        for (int r = 0; r < 4; ++r) {
            int lr = wm * 64 + mi * 16 + nib * 4 + r;
            float linv = 1.0f / Ll[lr];
#pragma unroll
            for (int ni = 0; ni < 4; ++ni) {
                int gcol = bcol + wn * 64 + ni * 16 + cc;
                Oj[(size_t)(brow + lr) * 512 + gcol] = (bf16)(acc[mi][ni][r] * linv);
            }
        }
    }
}

extern "C" void kernel_launch(void* const* d_in, const int* in_sizes, int n_in,
                              void* d_out, int out_size, void* d_ws, size_t ws_size,
                              hipStream_t stream)
{
    const float* x   = (const float*)d_in[0];
    const float* y   = (const float*)d_in[1];
    const float* ns  = (const float*)d_in[2];
    const float* nb  = (const float*)d_in[3];
    const float* n1s = (const float*)d_in[4];
    const float* n1b = (const float*)d_in[5];
    const float* wq  = (const float*)d_in[6];
    const float* bq  = (const float*)d_in[7];
    const float* wk  = (const float*)d_in[8];
    const float* bk  = (const float*)d_in[9];
    const float* wv  = (const float*)d_in[10];
    const float* bv  = (const float*)d_in[11];
    const float* wp  = (const float*)d_in[12];
    const float* bp  = (const float*)d_in[13];
    float* out = (float*)d_out;

    char* ws = (char*)d_ws;
    bf16* wbf  = (bf16*)ws;                          // 2 MB weights bf16
    float* bpk = (float*)(ws + 2097152);             // 8 KB biases
    bf16* ynT = (bf16*)(ws + 2105344);               // [b][hw][c]
    bf16* hnT = ynT + 8388608;
    bf16* qT  = hnT + 8388608;
    bf16* kT  = qT  + 8388608;
    bf16* v   = kT  + 8388608;                       // [b][c][hw]
    float* stats = (float*)ynT;                      // ynT dead after q/k conv
    bf16* aoT = qT;                                  // qT dead after QK^T
    bf16* P   = (bf16*)(ws + 2105344 + 5ull * 16777216);   // 32 MB bf16

    const size_t sBC = (size_t)kHW * kC;
    const float scl = 0.044194173824159216f;         // 512^-0.5

    // GN(x)->hnT, GN(y)->ynT, weight pack — one launch
    gn2w_kernel<<<2048, 256, 0, stream>>>(
        x, ns, nb, hnT, y, n1s, n1b, ynT,
        wq, wk, wv, wp, bq, bk, bv, bp, wbf, bpk);

    // q & k convs fused (jobs 0/1): out_T[i][o] = in_T[i][c]·W[o][c] + b[o]
    gemm256<2, false, bf16, false, 2, 64><<<256, 512, 0, stream>>>(
        ynT, 8388608, 512, wbf, 262144, 512, qT, 8388608, 512,
        bpk, 512, nullptr, 0, 1.f, nullptr);
    // v conv per batch: v[o][n] = wv[o][c]·hnT[n][c] + bv[o]
    gemm128<1, false, bf16, 4, 4><<<256, 512, 0, stream>>>(
        wbf + 2 * 262144, 0, 512, hnT, sBC, 512, v, sBC, 1024,
        bpk + 1024, 0, nullptr, 0);
    // QK^T -> P_local bf16 + (M,L) stats per (row, bx)
    gemm256<0, false, bf16, true, 4, 4><<<256, 512, 0, stream>>>(
        qT, sBC, 512, kT, sBC, 512, P, 1048576, 1024,
        bpk, 0, nullptr, 0, scl, stats);
    // fused softmax-finish + PV -> aoT [b][hw][c]
    pv_gemm<<<256, 512, 0, stream>>>(P, stats, v, aoT);
    // proj + bias + residual
    gemm128<1, true, float, 4, 4><<<256, 512, 0, stream>>>(
        wbf + 3 * 262144, 0, 512, aoT, sBC, 512, out, sBC, 1024,
        bpk + 1536, 0, x, sBC);
}

// Round 11
// 125.305 us; speedup vs baseline: 1.2101x; 1.1123x over previous
//
#include <hip/hip_runtime.h>
#include <hip/hip_bf16.h>

typedef __bf16 bf16;
typedef __bf16 bf16x8 __attribute__((ext_vector_type(8)));
typedef __bf16 bf16x4 __attribute__((ext_vector_type(4)));
typedef float f32x4 __attribute__((ext_vector_type(4)));
typedef unsigned short u16;
typedef unsigned short u16x8 __attribute__((ext_vector_type(8)));

constexpr int kHW = 1024;
constexpr int kC  = 512;

__device__ inline float wave_sum(float v) {
#pragma unroll
    for (int o = 32; o; o >>= 1) v += __shfl_xor(v, o, 64);
    return v;
}

__device__ inline float b2f(u16 u) {
    union { float f; unsigned i; } z; z.i = ((unsigned)u) << 16; return z.f;
}

__device__ inline void gload_lds16(const void* g, void* l) {
    __builtin_amdgcn_global_load_lds(
        (const __attribute__((address_space(1))) void*)g,
        (__attribute__((address_space(3))) void*)l, 16, 0, 0);
}

#define VMCNT(n) asm volatile("s_waitcnt vmcnt(" #n ")" ::: "memory")
#define SBAR __builtin_amdgcn_s_barrier()
#define NOP do {} while (0)

// ===== fused: GroupNorm(x)->hnT, GroupNorm(y)->ynT, weights f32->bf16 =====
__global__ __launch_bounds__(256) void gn2w_kernel(
    const float* __restrict__ x0, const float* __restrict__ s0,
    const float* __restrict__ b0, bf16* __restrict__ o0,
    const float* __restrict__ x1, const float* __restrict__ s1,
    const float* __restrict__ b1, bf16* __restrict__ o1,
    const float* __restrict__ wq, const float* __restrict__ wk,
    const float* __restrict__ wv, const float* __restrict__ wp,
    const float* __restrict__ bq, const float* __restrict__ bk,
    const float* __restrict__ bv, const float* __restrict__ bp,
    bf16* __restrict__ wdst, float* __restrict__ bpk)
{
    int bid = blockIdx.x;
    int t = threadIdx.x;
    if (bid >= 1024) {                    // weight-pack blocks
        int i = (bid - 1024) * 256 + t;
        wdst[i]            = (bf16)wq[i];
        wdst[262144 + i]   = (bf16)wk[i];
        wdst[2*262144 + i] = (bf16)wv[i];
        wdst[3*262144 + i] = (bf16)wp[i];
        if (i < 2048) {
            int j = i >> 9, c = i & 511;
            const float* s = j == 0 ? bq : j == 1 ? bk : j == 2 ? bv : bp;
            bpk[i] = s[c];
        }
        return;
    }

    __shared__ u16 xs[16][1032];          // raw bf16 tile, 33KB
    __shared__ float red[8];
    __shared__ float ab[2][16];

    // XCD-locality decode: xcd = bid&7 owns 4 (sel,b) pairs, each with all 32 g
    int xcd = bid & 7, idx = bid >> 3;    // idx 0..127
    int pair = xcd * 4 + (idx >> 5);      // 0..31
    int g = idx & 31;
    int sel = pair >> 4;
    int b = pair & 15;

    const float* x = sel ? x1 : x0;
    const float* scale = sel ? s1 : s0;
    const float* bias  = sel ? b1 : b0;
    bf16* outT = sel ? o1 : o0;

    int c0 = g * 16;
    const float* xg = x + ((size_t)b * kC + c0) * kHW;

    float s = 0.f, s2 = 0.f;
    const float4* xg4 = reinterpret_cast<const float4*>(xg);
#pragma unroll
    for (int i = 0; i < 16; ++i) {
        float4 v = xg4[t + i * 256];      // channel i, col 4t
        bf16x4 r;
        r[0] = (bf16)v.x; r[1] = (bf16)v.y; r[2] = (bf16)v.z; r[3] = (bf16)v.w;
        *reinterpret_cast<bf16x4*>(&xs[i][t * 4]) = r;
        s  += v.x + v.y + v.z + v.w;
        s2 += v.x*v.x + v.y*v.y + v.z*v.z + v.w*v.w;
    }
    s = wave_sum(s); s2 = wave_sum(s2);
    int lane = t & 63, wid = t >> 6;
    if (!lane) { red[wid] = s; red[4 + wid] = s2; }
    __syncthreads();
    float ts = red[0] + red[1] + red[2] + red[3];
    float t2 = red[4] + red[5] + red[6] + red[7];
    float mean = ts * (1.f / 16384.f);
    float var  = t2 * (1.f / 16384.f) - mean * mean;
    float inv  = rsqrtf(var + 1e-6f);

    if (t < 16) {
        float a = inv * scale[c0 + t];
        ab[0][t] = a;
        ab[1][t] = bias[c0 + t] - mean * a;
    }
    __syncthreads();

    int cg = t & 3, spw = t >> 2;         // 4 channel-groups x 64 rows
    float a0 = ab[0][cg*4],   a1 = ab[0][cg*4+1],
          a2 = ab[0][cg*4+2], a3 = ab[0][cg*4+3];
    float d0 = ab[1][cg*4],   d1 = ab[1][cg*4+1],
          d2 = ab[1][cg*4+2], d3 = ab[1][cg*4+3];
    bf16* ob = outT + (size_t)b * kHW * kC + c0 + cg * 4;
#pragma unroll
    for (int i = 0; i < 16; ++i) {
        int sp = spw + i * 64;
        bf16x4 w;
        w[0] = (bf16)(b2f(xs[cg*4 + 0][sp]) * a0 + d0);
        w[1] = (bf16)(b2f(xs[cg*4 + 1][sp]) * a1 + d1);
        w[2] = (bf16)(b2f(xs[cg*4 + 2][sp]) * a2 + d2);
        w[3] = (bf16)(b2f(xs[cg*4 + 3][sp]) * a3 + d3);
        *reinterpret_cast<bf16x4*>(ob + (size_t)sp * kC) = w;
    }
}

// ======== 256x256 8-phase NT GEMM, K=512. Schedule v2 =====================
// STATS (no-max softmax): writes P = exp(alpha*acc) as C, plus per-(row,bx)
// partial row-sum L into statsOut[(job*1024+row)*4 + bx].
template <int BIAS, bool RESID, typename OUT_T, bool STATS, int NBX, int NBY>
__global__ __launch_bounds__(512, 2) void gemm256(
    const bf16* __restrict__ Ab, size_t sA, int lda,
    const bf16* __restrict__ Bb, size_t sB, int ldb,
    OUT_T* __restrict__ Cb, size_t sC, int ldc,
    const float* __restrict__ biasB, int sBias,
    const float* __restrict__ residB, size_t sR,
    float alpha, float* __restrict__ statsOut)
{
    __shared__ u16 lds[65536];           // 128KB: A 8x8KB (2slot x 4q), B same
    constexpr int NT = 8;                // K = 512

    int bid = blockIdx.x, nwg = gridDim.x;
    int swz = (bid & 7) * (nwg >> 3) + (bid >> 3);
    int job = swz / (NBX * NBY), rem = swz % (NBX * NBY);
    int by = rem / NBX, bx = rem % NBX;
    int brow = by * 256, bcol = bx * 256;

    const u16* Au = reinterpret_cast<const u16*>(Ab + (size_t)job * sA);
    const u16* Bu = reinterpret_cast<const u16*>(Bb + (size_t)job * sB);

    int t = threadIdx.x;
    int lane = t & 63, w = t >> 6;
    int wm = w >> 2, wn = w & 3;
    int cc = lane & 15, nib = lane >> 4;

    int trow = t >> 3;                               // 0..63
    int gsrc = ((t & 7) ^ (trow & 7)) * 8;           // pre-swizzled src granule
    const u16* Asrc = Au + (size_t)(brow + trow) * lda + gsrc;
    const u16* Bsrc = Bu + (size_t)(bcol + trow) * ldb + gsrc;
    u16* LDSA = lds;
    u16* LDSB = lds + 32768;

#define STAGE_A(TL, Q) gload_lds16(Asrc + (size_t)(Q) * 64 * lda + (TL) * 64, \
                                   LDSA + (((TL)&1)*4 + (Q)) * 4096 + t * 8)
#define STAGE_B(TL, Q) gload_lds16(Bsrc + (size_t)(Q) * 64 * ldb + (TL) * 64, \
                                   LDSB + (((TL)&1)*4 + (Q)) * 4096 + t * 8)

    f32x4 acc[8][4] = {};
    bf16x8 afr[4][2], bfr[4][2];

#define PHASE(MH, NH, TL, STG, WTC)                                           \
  {                                                                           \
    if ((NH) == 0) {                                                          \
      _Pragma("unroll") for (int mi = 0; mi < 4; ++mi)                        \
      _Pragma("unroll") for (int kx = 0; kx < 2; ++kx)                        \
        afr[mi][kx] = *reinterpret_cast<const bf16x8*>(LDSA +                 \
            (((TL)&1)*4 + wm*2 + (MH)) * 4096 + (mi*16 + cc) * 64 +           \
            (((nib + kx*4) ^ (cc & 7)) * 8));                                 \
    }                                                                         \
    if ((MH) == 0) {                                                          \
      _Pragma("unroll") for (int ni = 0; ni < 2; ++ni)                        \
      _Pragma("unroll") for (int kx = 0; kx < 2; ++kx)                        \
        bfr[(NH)*2 + ni][kx] = *reinterpret_cast<const bf16x8*>(LDSB +        \
            (((TL)&1)*4 + wn) * 4096 + (((NH)*2 + ni)*16 + cc) * 64 +         \
            (((nib + kx*4) ^ (cc & 7)) * 8));                                 \
    }                                                                         \
    STG;                                                                      \
    SBAR;                                                                     \
    __builtin_amdgcn_s_setprio(1);                                            \
    _Pragma("unroll") for (int mi = 0; mi < 4; ++mi)                          \
    _Pragma("unroll") for (int ni = 0; ni < 2; ++ni)                          \
    _Pragma("unroll") for (int kx = 0; kx < 2; ++kx)                          \
      acc[(MH)*4 + mi][(NH)*2 + ni] = __builtin_amdgcn_mfma_f32_16x16x32_bf16(\
          afr[mi][kx], bfr[(NH)*2 + ni][kx], acc[(MH)*4 + mi][(NH)*2 + ni],   \
          0, 0, 0);                                                           \
    __builtin_amdgcn_s_setprio(0);                                            \
    WTC;                                                                      \
    SBAR;                                                                     \
  }

    // prologue: tiles 0 and 1 fully staged; wait for tile 0
    STAGE_A(0, 0); STAGE_A(0, 2); STAGE_B(0, 0); STAGE_B(0, 1);
    STAGE_B(0, 2); STAGE_B(0, 3); STAGE_A(0, 1); STAGE_A(0, 3);
    STAGE_A(1, 0); STAGE_A(1, 2); STAGE_B(1, 0); STAGE_B(1, 1);
    STAGE_B(1, 2); STAGE_B(1, 3); STAGE_A(1, 1); STAGE_A(1, 3);
    VMCNT(8);
    SBAR;

#pragma unroll
    for (int kt = 0; kt < NT; ++kt) {
        PHASE(0, 0, kt, NOP, NOP);
        PHASE(0, 1, kt,
              if (kt + 2 < NT) { STAGE_A(kt + 2, 0); STAGE_A(kt + 2, 2); },
              NOP);
        PHASE(1, 0, kt,
              if (kt + 2 < NT) { STAGE_B(kt + 2, 0); STAGE_B(kt + 2, 1); },
              NOP);
        PHASE(1, 1, kt,
              if (kt + 2 < NT) { STAGE_B(kt + 2, 2); STAGE_B(kt + 2, 3);
                                 STAGE_A(kt + 2, 1); STAGE_A(kt + 2, 3); },
              if (kt < NT - 2) { VMCNT(8); } else if (kt == NT - 2) { VMCNT(0); });
    }
#undef PHASE
#undef STAGE_A
#undef STAGE_B

#pragma unroll
    for (int m = 0; m < 8; ++m)
#pragma unroll
        for (int n = 0; n < 4; ++n)
#pragma unroll
            for (int r = 0; r < 4; ++r)
                acc[m][n][r] *= alpha;

    if constexpr (STATS) {
        // no-max softmax: acc -> exp(acc); partial row-sum over this block's
        // 256 cols; one float per (row, bx).
        float* sredS = reinterpret_cast<float*>(lds);          // [4][256]
#pragma unroll
        for (int m = 0; m < 8; ++m)
#pragma unroll
            for (int r = 0; r < 4; ++r) {
                float s_ = 0.f;
#pragma unroll
                for (int n = 0; n < 4; ++n) {
                    float e = __expf(acc[m][n][r]);
                    acc[m][n][r] = e;
                    s_ += e;
                }
                s_ += __shfl_xor(s_, 1, 64);
                s_ += __shfl_xor(s_, 2, 64);
                s_ += __shfl_xor(s_, 4, 64);
                s_ += __shfl_xor(s_, 8, 64);
                if (cc == 0)
                    sredS[wn * 256 + wm * 128 + m * 16 + nib * 4 + r] = s_;
            }
        __syncthreads();
        if (t < 256) {
            float L = sredS[t] + sredS[256 + t] + sredS[512 + t] + sredS[768 + t];
            statsOut[((size_t)(job * 1024 + brow + t)) * 4 + bx] = L;
        }
    }

    OUT_T* Cj = Cb + (size_t)job * sC;
    const float* bias = biasB + (size_t)job * sBias;
#pragma unroll
    for (int m = 0; m < 8; ++m) {
#pragma unroll
        for (int n = 0; n < 4; ++n) {
#pragma unroll
            for (int r = 0; r < 4; ++r) {
                int grow = brow + wm * 128 + m * 16 + nib * 4 + r;
                int gcol = bcol + wn * 64 + n * 16 + cc;
                float vv = acc[m][n][r];
                if (BIAS == 1) vv += bias[grow];
                if (BIAS == 2) vv += bias[gcol];
                if (RESID)     vv += residB[(size_t)job * sR + (size_t)grow * ldc + gcol];
                Cj[(size_t)grow * ldc + gcol] = (OUT_T)vv;
            }
        }
    }
}

// ======== 128x256 NT GEMM, BK=64, ring-3 slots, 1 barrier/tile ============
// NT = K/64 (template). RSCALE: multiply each output row by
// 1 / sum(statsIn[(job*1024+row)*4 + 0..3])  (softmax-finish for PV).
template <int BIAS, bool RESID, typename OUT_T, int NBX, int NBY, int NT, bool RSCALE>
__global__ __launch_bounds__(512, 2) void gemm128(
    const bf16* __restrict__ Ab, size_t sA, int lda,
    const bf16* __restrict__ Bb, size_t sB, int ldb,
    OUT_T* __restrict__ Cb, size_t sC, int ldc,
    const float* __restrict__ biasB, int sBias,
    const float* __restrict__ residB, size_t sR,
    const float* __restrict__ statsIn)
{
    __shared__ u16 lds[3 * 24576];       // 144KB: 3 slots x (A 16KB + B 32KB)

    int bid = blockIdx.x, nwg = gridDim.x;
    int swz = (bid & 7) * (nwg >> 3) + (bid >> 3);
    int job = swz / (NBX * NBY), rem = swz % (NBX * NBY);
    int by = rem / NBX, bx = rem % NBX;
    int brow = by * 128, bcol = bx * 256;

    const u16* Au = reinterpret_cast<const u16*>(Ab + (size_t)job * sA);
    const u16* Bu = reinterpret_cast<const u16*>(Bb + (size_t)job * sB);

    int t = threadIdx.x;
    int lane = t & 63, w = t >> 6;
    int wm = w >> 2, wn = w & 3;         // wm 0..1 (M), wn 0..3 (N)
    int cc = lane & 15, nib = lane >> 4;

    int trow = t >> 3;
    int gsrc = ((t & 7) ^ (trow & 7)) * 8;
    const u16* Asrc = Au + (size_t)(brow + trow) * lda + gsrc;
    const u16* Bsrc = Bu + (size_t)(bcol + trow) * ldb + gsrc;

#define STG_T(TL) {                                                           \
    u16* sl_ = lds + ((TL) % 3) * 24576;                                      \
    gload_lds16(Asrc + (TL) * 64,                          sl_ + t * 8);      \
    gload_lds16(Asrc + (size_t)64 * lda + (TL) * 64,       sl_ + 4096 + t*8); \
    gload_lds16(Bsrc + (TL) * 64,                          sl_ + 8192 + t*8); \
    gload_lds16(Bsrc + (size_t)64  * ldb + (TL) * 64,      sl_ + 12288 + t*8);\
    gload_lds16(Bsrc + (size_t)128 * ldb + (TL) * 64,      sl_ + 16384 + t*8);\
    gload_lds16(Bsrc + (size_t)192 * ldb + (TL) * 64,      sl_ + 20480 + t*8);\
  }

    f32x4 acc[4][4] = {};

    STG_T(0); STG_T(1);
    VMCNT(6);
    SBAR;

#pragma unroll
    for (int kt = 0; kt < NT; ++kt) {
        if (kt + 2 < NT) STG_T(kt + 2);
        const u16* sb = lds + (kt % 3) * 24576;
        bf16x8 a[4][2], b[4][2];
#pragma unroll
        for (int mi = 0; mi < 4; ++mi)
#pragma unroll
            for (int kx = 0; kx < 2; ++kx)
                a[mi][kx] = *reinterpret_cast<const bf16x8*>(sb +
                    wm * 4096 + (mi*16 + cc) * 64 + (((nib + kx*4) ^ (cc & 7)) * 8));
#pragma unroll
        for (int ni = 0; ni < 4; ++ni)
#pragma unroll
            for (int kx = 0; kx < 2; ++kx)
                b[ni][kx] = *reinterpret_cast<const bf16x8*>(sb + 8192 +
                    wn * 4096 + (ni*16 + cc) * 64 + (((nib + kx*4) ^ (cc & 7)) * 8));
        __builtin_amdgcn_s_setprio(1);
#pragma unroll
        for (int mi = 0; mi < 4; ++mi)
#pragma unroll
            for (int ni = 0; ni < 4; ++ni)
#pragma unroll
                for (int kx = 0; kx < 2; ++kx)
                    acc[mi][ni] = __builtin_amdgcn_mfma_f32_16x16x32_bf16(
                        a[mi][kx], b[ni][kx], acc[mi][ni], 0, 0, 0);
        __builtin_amdgcn_s_setprio(0);
        if (kt < NT - 2) { VMCNT(6); } else if (kt == NT - 2) { VMCNT(0); }
        SBAR;
    }
#undef STG_T

    float* Ls = reinterpret_cast<float*>(lds);   // tiles dead after loop
    if constexpr (RSCALE) {
        __syncthreads();
        if (t < 128) {
            float4 sv = *reinterpret_cast<const float4*>(
                statsIn + ((size_t)(job * 1024 + brow + t)) * 4);
            Ls[t] = 1.0f / (sv.x + sv.y + sv.z + sv.w);
        }
        __syncthreads();
    }

    OUT_T* Cj = Cb + (size_t)job * sC;
    const float* bias = biasB + (size_t)job * sBias;
#pragma unroll
    for (int mi = 0; mi < 4; ++mi) {
#pragma unroll
        for (int ni = 0; ni < 4; ++ni) {
#pragma unroll
            for (int r = 0; r < 4; ++r) {
                int grow = brow + wm * 64 + mi * 16 + nib * 4 + r;
                int gcol = bcol + wn * 64 + ni * 16 + cc;
                float vv = acc[mi][ni][r];
                if constexpr (RSCALE) vv *= Ls[wm * 64 + mi * 16 + nib * 4 + r];
                if (BIAS == 1) vv += bias[grow];
                if (BIAS == 2) vv += bias[gcol];
                if (RESID)     vv += residB[(size_t)job * sR + (size_t)grow * ldc + gcol];
                Cj[(size_t)grow * ldc + gcol] = (OUT_T)vv;
            }
        }
    }
}

extern "C" void kernel_launch(void* const* d_in, const int* in_sizes, int n_in,
                              void* d_out, int out_size, void* d_ws, size_t ws_size,
                              hipStream_t stream)
{
    const float* x   = (const float*)d_in[0];
    const float* y   = (const float*)d_in[1];
    const float* ns  = (const float*)d_in[2];
    const float* nb  = (const float*)d_in[3];
    const float* n1s = (const float*)d_in[4];
    const float* n1b = (const float*)d_in[5];
    const float* wq  = (const float*)d_in[6];
    const float* bq  = (const float*)d_in[7];
    const float* wk  = (const float*)d_in[8];
    const float* bk  = (const float*)d_in[9];
    const float* wv  = (const float*)d_in[10];
    const float* bv  = (const float*)d_in[11];
    const float* wp  = (const float*)d_in[12];
    const float* bp  = (const float*)d_in[13];
    float* out = (float*)d_out;

    char* ws = (char*)d_ws;
    bf16* wbf  = (bf16*)ws;                          // 2 MB weights bf16
    float* bpk = (float*)(ws + 2097152);             // 8 KB biases
    bf16* ynT = (bf16*)(ws + 2105344);               // [b][hw][c]
    bf16* hnT = ynT + 8388608;
    bf16* qT  = hnT + 8388608;
    bf16* kT  = qT  + 8388608;
    bf16* v   = kT  + 8388608;                       // [b][c][hw]
    float* stats = (float*)ynT;                      // ynT dead after q/k conv
    bf16* aoT = qT;                                  // qT dead after QK^T
    bf16* P   = (bf16*)(ws + 2105344 + 5ull * 16777216);   // 32 MB bf16

    const size_t sBC = (size_t)kHW * kC;
    const float scl = 0.044194173824159216f;         // 512^-0.5

    // GN(x)->hnT, GN(y)->ynT, weight pack — one launch
    gn2w_kernel<<<2048, 256, 0, stream>>>(
        x, ns, nb, hnT, y, n1s, n1b, ynT,
        wq, wk, wv, wp, bq, bk, bv, bp, wbf, bpk);

    // q & k convs fused (jobs 0/1): out_T[i][o] = in_T[i][c]·W[o][c] + b[o]
    gemm256<2, false, bf16, false, 2, 64><<<256, 512, 0, stream>>>(
        ynT, 8388608, 512, wbf, 262144, 512, qT, 8388608, 512,
        bpk, 512, nullptr, 0, 1.f, nullptr);
    // v conv per batch: v[o][n] = wv[o][c]·hnT[n][c] + bv[o]
    gemm128<1, false, bf16, 4, 4, 8, false><<<256, 512, 0, stream>>>(
        wbf + 2 * 262144, 0, 512, hnT, sBC, 512, v, sBC, 1024,
        bpk + 1024, 0, nullptr, 0, nullptr);
    // QK^T -> P = exp(scl*S) bf16 + partial row-sums L per (row, bx)
    gemm256<0, false, bf16, true, 4, 4><<<256, 512, 0, stream>>>(
        qT, sBC, 512, kT, sBC, 512, P, 1048576, 1024,
        bpk, 0, nullptr, 0, scl, stats);
    // PV as pure GEMM (K=1024) + 1/L row-scale: aoT[i][c] = P[i][:]·v[c][:] / L_i
    gemm128<0, false, bf16, 2, 8, 16, true><<<256, 512, 0, stream>>>(
        P, (size_t)1048576, 1024, v, sBC, 1024, aoT, sBC, 512,
        bpk, 0, nullptr, 0, stats);
    // proj + bias + residual
    gemm128<1, true, float, 4, 4, 8, false><<<256, 512, 0, stream>>>(
        wbf + 3 * 262144, 0, 512, aoT, sBC, 512, out, sBC, 1024,
        bpk + 1536, 0, x, sBC, nullptr);
}